// Round 2
// baseline (3676.635 us; speedup 1.0000x reference)
//
#include <hip/hip_runtime.h>
#include <hip/hip_bf16.h>

// ---------------------------------------------------------------------------
// TokenPoseWithShiftedWindow: fp32 correctness-first implementation.
// B=4, N=512, C=384, H=6, HD=64, IFF=1536, 4 dense + 4 swin blocks, decoder.
// ---------------------------------------------------------------------------

struct GemmP {
  const float* A; const float* B; const float* bias; float* C;
  const float* e1; const float* e2; const float* e3; const float* e4;
  int M, N, K, ZH;
  long lda, ldbK, ldbN, ldc;
  long aSb, aSh, bSb, bSh, cSb, cSh;
  float scale;
};

// MODE: 0=store(+bias) 1=+bias+posemb 2=residual+= 3=relu(+bias)
//       4=scale-store 5=bnrelu+deconv1-scatter 6=bnrelu row-major store
template<int MODE>
__global__ __launch_bounds__(256) void gemm_k(GemmP p) {
  const int z = blockIdx.z;
  const int zb = z / p.ZH, zh = z - zb * p.ZH;
  const float* A = p.A + zb * p.aSb + zh * p.aSh;
  const float* B = p.B + zb * p.bSb + zh * p.bSh;
  float* C = p.C + zb * p.cSb + zh * p.cSh;
  const int m0 = blockIdx.y * 64, n0 = blockIdx.x * 64;
  __shared__ __align__(16) float As[16][68];
  __shared__ __align__(16) float Bs[16][68];
  const int tid = threadIdx.x;
  const int tx = tid & 15, ty = tid >> 4;
  const int arow = tid >> 2, akg = (tid & 3) << 2;
  const int bkr = tid >> 4, bng = (tid & 15) << 2;
  float acc[4][4] = {};
  for (int k0 = 0; k0 < p.K; k0 += 16) {
    float4 av = *(const float4*)(A + (long)(m0 + arow) * p.lda + (k0 + akg));
    As[akg + 0][arow] = av.x;
    As[akg + 1][arow] = av.y;
    As[akg + 2][arow] = av.z;
    As[akg + 3][arow] = av.w;
    if (p.ldbN == 1) {
      *(float4*)&Bs[bkr][bng] = *(const float4*)(B + (long)(k0 + bkr) * p.ldbK + (n0 + bng));
    } else {
      #pragma unroll
      for (int u = 0; u < 4; u++)
        Bs[bkr][bng + u] = B[(long)(k0 + bkr) * p.ldbK + (long)(n0 + bng + u) * p.ldbN];
    }
    __syncthreads();
    #pragma unroll
    for (int kk = 0; kk < 16; kk++) {
      float4 a = *(const float4*)&As[kk][ty << 2];
      float4 b = *(const float4*)&Bs[kk][tx << 2];
      acc[0][0] += a.x * b.x; acc[0][1] += a.x * b.y; acc[0][2] += a.x * b.z; acc[0][3] += a.x * b.w;
      acc[1][0] += a.y * b.x; acc[1][1] += a.y * b.y; acc[1][2] += a.y * b.z; acc[1][3] += a.y * b.w;
      acc[2][0] += a.z * b.x; acc[2][1] += a.z * b.y; acc[2][2] += a.z * b.z; acc[2][3] += a.z * b.w;
      acc[3][0] += a.w * b.x; acc[3][1] += a.w * b.y; acc[3][2] += a.w * b.z; acc[3][3] += a.w * b.w;
    }
    __syncthreads();
  }
  const int mr = m0 + (ty << 2), nc = n0 + (tx << 2);
  #pragma unroll
  for (int r = 0; r < 4; r++) {
    float4 v;
    v.x = acc[r][0]; v.y = acc[r][1]; v.z = acc[r][2]; v.w = acc[r][3];
    if constexpr (MODE == 4) {
      v.x *= p.scale; v.y *= p.scale; v.z *= p.scale; v.w *= p.scale;
      *(float4*)(C + (long)(mr + r) * p.ldc + nc) = v;
    } else if constexpr (MODE <= 3) {
      if (p.bias) { v.x += p.bias[nc]; v.y += p.bias[nc + 1]; v.z += p.bias[nc + 2]; v.w += p.bias[nc + 3]; }
      if constexpr (MODE == 1) {
        const float* pos = p.e1 + (long)((mr + r) & 511) * 384 + nc;
        v.x += pos[0]; v.y += pos[1]; v.z += pos[2]; v.w += pos[3];
      }
      if constexpr (MODE == 3) {
        v.x = fmaxf(v.x, 0.f); v.y = fmaxf(v.y, 0.f); v.z = fmaxf(v.z, 0.f); v.w = fmaxf(v.w, 0.f);
      }
      float4* dst = (float4*)(C + (long)(mr + r) * p.ldc + nc);
      if constexpr (MODE == 2) {
        float4 o = *dst;
        v.x += o.x; v.y += o.y; v.z += o.z; v.w += o.w;
      }
      *dst = v;
    } else { // 5, 6 : bias + batchnorm + relu
      float vv[4] = {v.x, v.y, v.z, v.w};
      #pragma unroll
      for (int c = 0; c < 4; c++) {
        int n = nc + c;
        float raw = vv[c] + p.bias[n];
        float val = (raw - p.e3[n]) * rsqrtf(p.e4[n] + 1e-5f) * p.e1[n] + p.e2[n];
        vv[c] = fmaxf(val, 0.f);
      }
      v.x = vv[0]; v.y = vv[1]; v.z = vv[2]; v.w = vv[3];
      if constexpr (MODE == 6) {
        *(float4*)(C + (long)(mr + r) * p.ldc + nc) = v;
      } else { // deconv1 scatter into token-major [B,16,16,16,C]
        int m = mr + r;
        int b = m >> 9, hwd = m & 511;
        int h = hwd >> 6, w = (hwd >> 3) & 7, d = hwd & 7;
        int i = zh >> 2, j = (zh >> 1) & 1, k = zh & 1;
        long tokn = (long)b * 4096 + (2 * h + i) * 256 + (2 * w + j) * 16 + (2 * d + k);
        *(float4*)(C + tokn * 384 + nc) = v;
      }
    }
  }
}

// LayerNorm over C=384; 1 wave per row, 4 rows per block.
__global__ __launch_bounds__(256) void ln_k(const float* __restrict__ x, const float* __restrict__ g,
                                            const float* __restrict__ b, float* __restrict__ y) {
  const int row = (blockIdx.x << 2) + (threadIdx.x >> 6);
  const int lane = threadIdx.x & 63;
  const float* xr = x + (long)row * 384;
  float v[6]; float s = 0.f;
  #pragma unroll
  for (int i = 0; i < 6; i++) { v[i] = xr[lane + (i << 6)]; s += v[i]; }
  #pragma unroll
  for (int o = 32; o >= 1; o >>= 1) s += __shfl_xor(s, o);
  const float mean = s * (1.f / 384.f);
  float q = 0.f;
  #pragma unroll
  for (int i = 0; i < 6; i++) { float dd = v[i] - mean; q += dd * dd; }
  #pragma unroll
  for (int o = 32; o >= 1; o >>= 1) q += __shfl_xor(q, o);
  const float rstd = rsqrtf(q * (1.f / 384.f) + 1e-5f);
  float* yr = y + (long)row * 384;
  #pragma unroll
  for (int i = 0; i < 6; i++) {
    int c = lane + (i << 6);
    yr[c] = (v[i] - mean) * rstd * g[c] + b[c];
  }
}

// Row softmax over 512 columns (scores are 12288 rows).
__global__ __launch_bounds__(256) void softmax_k(float* __restrict__ s) {
  float* row = s + (long)blockIdx.x * 512;
  const int tid = threadIdx.x;
  float v0 = row[tid], v1 = row[tid + 256];
  float m = fmaxf(v0, v1);
  #pragma unroll
  for (int o = 32; o >= 1; o >>= 1) m = fmaxf(m, __shfl_xor(m, o));
  __shared__ float r1[4], r2[4];
  if ((tid & 63) == 0) r1[tid >> 6] = m;
  __syncthreads();
  m = fmaxf(fmaxf(r1[0], r1[1]), fmaxf(r1[2], r1[3]));
  float e0 = __expf(v0 - m), e1 = __expf(v1 - m);
  float sm = e0 + e1;
  #pragma unroll
  for (int o = 32; o >= 1; o >>= 1) sm += __shfl_xor(sm, o);
  if ((tid & 63) == 0) r2[tid >> 6] = sm;
  __syncthreads();
  const float inv = 1.f / (r2[0] + r2[1] + r2[2] + r2[3]);
  row[tid] = e0 * inv;
  row[tid + 256] = e1 * inv;
}

// Shifted-window attention: 1 block (64 lanes) per (batch, window, head).
__global__ __launch_bounds__(64) void swin_k(const float* __restrict__ qkv, float* __restrict__ attno) {
  const int blk = blockIdx.x;
  const int h = blk % 6; const int bw = blk / 6;
  const int b = bw >> 6, win = bw & 63;
  const int wh = win >> 4, ww = (win >> 2) & 3, wd = win & 3;
  const int lane = threadIdx.x;
  __shared__ float qs[8][68], ks[8][68], vs[8][68], attw[8][8];
  __shared__ int ntok[8];
  if (lane < 8) {
    int i = lane >> 2, j = (lane >> 1) & 1, k = lane & 1;
    int oh = (2 * wh + i + 1) & 7, ow = (2 * ww + j + 1) & 7, od = (2 * wd + k + 1) & 7;
    ntok[lane] = oh * 64 + ow * 8 + od;  // roll(-1) gather; output scatters back to same token
  }
  __syncthreads();
  #pragma unroll
  for (int t = 0; t < 8; t++) {
    long base = ((long)b * 512 + ntok[t]) * 1152 + h * 64 + lane;
    qs[t][lane] = qkv[base];
    ks[t][lane] = qkv[base + 384];
    vs[t][lane] = qkv[base + 768];
  }
  __syncthreads();
  const int tq = lane >> 3, tm = lane & 7;
  float sc = 0.f;
  #pragma unroll 16
  for (int d = 0; d < 64; d++) sc += qs[tq][d] * ks[tm][d];
  sc *= 0.125f;
  float mx = sc;
  mx = fmaxf(mx, __shfl_xor(mx, 4));
  mx = fmaxf(mx, __shfl_xor(mx, 2));
  mx = fmaxf(mx, __shfl_xor(mx, 1));
  float e = __expf(sc - mx);
  float sm = e;
  sm += __shfl_xor(sm, 4); sm += __shfl_xor(sm, 2); sm += __shfl_xor(sm, 1);
  attw[tq][tm] = e / sm;
  __syncthreads();
  #pragma unroll
  for (int t = 0; t < 8; t++) {
    float o = 0.f;
    #pragma unroll
    for (int m = 0; m < 8; m++) o += attw[t][m] * vs[m][lane];
    attno[((long)b * 512 + ntok[t]) * 384 + h * 64 + lane] = o;
  }
}

// Patch im2col: [B, 512 patches, 512 elems]
__global__ __launch_bounds__(256) void im2col_k(const float* __restrict__ x, float* __restrict__ xp) {
  const int i = blockIdx.x * 256 + threadIdx.x;
  const int l = i & 511; const int m = i >> 9;
  const int b = m >> 9, n = m & 511;
  const int h = n >> 6, w = (n >> 3) & 7, d = n & 7;
  const int pi = l >> 6, pj = (l >> 3) & 7, pk = l & 7;
  xp[i] = x[(long)b * 262144 + (long)(h * 8 + pi) * 4096 + (w * 8 + pj) * 64 + (d * 8 + pk)];
}

// Repack per-head Q/K/V weights [H,C,HD] -> [C, 3*384] (q|k|v, col = h*64+d)
__global__ __launch_bounds__(256) void repack_k(const float* __restrict__ qw, const float* __restrict__ kw,
                                                const float* __restrict__ vw, float* __restrict__ wrep) {
  const int i = blockIdx.x * 256 + threadIdx.x;
  if (i >= 442368) return;
  const int c = i / 1152, r = i - c * 1152;
  const int s = r / 384, hd = r - s * 384;
  const int h = hd >> 6, d = hd & 63;
  const float* src = (s == 0) ? qw : (s == 1) ? kw : vw;
  wrep[i] = src[((long)h * 384 + c) * 64 + d];
}

// Final 1x1 conv: contract deconv2 activations [16384,384] with out_w [15,384],
// scatter to output voxels for kernel position ijk.
__global__ __launch_bounds__(256) void contract_k(const float* __restrict__ act, const float* __restrict__ ow,
                                                  const float* __restrict__ ob, float* __restrict__ out, int ijk) {
  __shared__ __align__(16) float tile[16][388];
  __shared__ __align__(16) float wsh[15][388];
  const int tid = threadIdx.x;
  for (int idx = tid; idx < 15 * 384; idx += 256) {
    int kp = idx / 384, c = idx - kp * 384;
    wsh[kp][c] = ow[idx];
  }
  const long row0 = (long)blockIdx.x << 4;
  for (int idx = tid; idx < 16 * 384; idx += 256) {
    int r = idx / 384, c = idx - r * 384;
    tile[r][c] = act[(row0 + r) * 384 + c];
  }
  __syncthreads();
  const int r = tid >> 4, kp = tid & 15;
  if (kp < 15) {
    float acc = 0.f;
    #pragma unroll 8
    for (int c = 0; c < 384; c += 4) {
      float4 a = *(const float4*)&tile[r][c];
      float4 w = *(const float4*)&wsh[kp][c];
      acc += a.x * w.x + a.y * w.y + a.z * w.z + a.w * w.w;
    }
    const int gm = (int)row0 + r;
    const int b = gm >> 12, h = (gm >> 8) & 15, w = (gm >> 4) & 15, d = gm & 15;
    const int i = ijk >> 2, j = (ijk >> 1) & 1, k = ijk & 1;
    const long o = ((long)(b * 15 + kp) << 15) + (2 * h + i) * 1024 + (2 * w + j) * 32 + (2 * d + k);
    out[o] = acc + ob[kp];
  }
}

// ---------------------------------------------------------------------------

static GemmP mk(const float* A, const float* B, const float* bias, float* C,
                int M, int N, int K, long lda, long ldbK, long ldbN, long ldc) {
  GemmP p{};
  p.A = A; p.B = B; p.bias = bias; p.C = C;
  p.e1 = p.e2 = p.e3 = p.e4 = nullptr;
  p.M = M; p.N = N; p.K = K; p.ZH = 1;
  p.lda = lda; p.ldbK = ldbK; p.ldbN = ldbN; p.ldc = ldc;
  p.aSb = p.aSh = p.bSb = p.bSh = p.cSb = p.cSh = 0;
  p.scale = 1.f;
  return p;
}

static void run_gemm(hipStream_t st, int mode, const GemmP& p, int gx, int gy, int gz) {
  dim3 g(gx, gy, gz), blk(256, 1, 1);
  switch (mode) {
    case 0: gemm_k<0><<<g, blk, 0, st>>>(p); break;
    case 1: gemm_k<1><<<g, blk, 0, st>>>(p); break;
    case 2: gemm_k<2><<<g, blk, 0, st>>>(p); break;
    case 3: gemm_k<3><<<g, blk, 0, st>>>(p); break;
    case 4: gemm_k<4><<<g, blk, 0, st>>>(p); break;
    case 5: gemm_k<5><<<g, blk, 0, st>>>(p); break;
    case 6: gemm_k<6><<<g, blk, 0, st>>>(p); break;
  }
}

extern "C" void kernel_launch(void* const* d_in, const int* in_sizes, int n_in,
                              void* d_out, int out_size, void* d_ws, size_t ws_size,
                              hipStream_t stream) {
  (void)in_sizes; (void)n_in; (void)out_size; (void)ws_size;
  const float* x        = (const float*)d_in[0];
  const float* patch_w  = (const float*)d_in[1];
  const float* patch_b  = (const float*)d_in[2];
  const float* pos_emb  = (const float*)d_in[3];
  const float* m_ln1_g  = (const float*)d_in[4];
  const float* m_ln1_b  = (const float*)d_in[5];
  const float* m_qw     = (const float*)d_in[6];
  const float* m_kw     = (const float*)d_in[7];
  const float* m_vw     = (const float*)d_in[8];
  const float* m_proj_w = (const float*)d_in[9];
  const float* m_proj_b = (const float*)d_in[10];
  const float* m_ln2_g  = (const float*)d_in[11];
  const float* m_ln2_b  = (const float*)d_in[12];
  const float* m_w1     = (const float*)d_in[13];
  const float* m_b1     = (const float*)d_in[14];
  const float* m_w2     = (const float*)d_in[15];
  const float* m_b2     = (const float*)d_in[16];
  const float* s_ln1_g  = (const float*)d_in[17];
  const float* s_ln1_b  = (const float*)d_in[18];
  const float* s_qkv_w  = (const float*)d_in[19];
  const float* s_qkv_b  = (const float*)d_in[20];
  const float* s_proj_w = (const float*)d_in[21];
  const float* s_proj_b = (const float*)d_in[22];
  const float* s_ln2_g  = (const float*)d_in[23];
  const float* s_ln2_b  = (const float*)d_in[24];
  const float* s_w1     = (const float*)d_in[25];
  const float* s_b1     = (const float*)d_in[26];
  const float* s_w2     = (const float*)d_in[27];
  const float* s_b2     = (const float*)d_in[28];
  const float* d1_w     = (const float*)d_in[29];
  const float* d1_b     = (const float*)d_in[30];
  const float* bn1_g    = (const float*)d_in[31];
  const float* bn1_b    = (const float*)d_in[32];
  const float* bn1_m    = (const float*)d_in[33];
  const float* bn1_v    = (const float*)d_in[34];
  const float* d2_w     = (const float*)d_in[35];
  const float* d2_b     = (const float*)d_in[36];
  const float* bn2_g    = (const float*)d_in[37];
  const float* bn2_b    = (const float*)d_in[38];
  const float* bn2_m    = (const float*)d_in[39];
  const float* bn2_v    = (const float*)d_in[40];
  const float* out_w    = (const float*)d_in[41];
  const float* out_b    = (const float*)d_in[42];
  float* out = (float*)d_out;

  // workspace arena (floats); total ~88 MB
  float* ws     = (float*)d_ws;
  float* tok    = ws;                   // 2048 x 384
  float* lnb    = tok + 786432;         // 2048 x 384
  float* qkv    = lnb + 786432;         // 2048 x 1152
  float* attno  = qkv + 2359296;        // 2048 x 384
  float* ffnh   = attno + 786432;       // 2048 x 1536
  float* scores = ffnh + 3145728;       // 4 x 6 x 512 x 512
  float* y1     = scores + 6291456;     // 16384 x 384 (token-major [B,16,16,16,C])
  float* wrep   = y1 + 6291456;         // 384 x 1152
  float* xp     = wrep + 442368;        // 2048 x 512
  float* out2   = scores;               // alias: scores dead by decoder time

  // ---- patch embedding + pos_emb ----
  im2col_k<<<4096, 256, 0, stream>>>(x, xp);
  {
    GemmP p = mk(xp, patch_w, patch_b, tok, 2048, 384, 512, 512, 1, 512, 384);
    p.e1 = pos_emb;
    run_gemm(stream, 1, p, 6, 32, 1);
  }

  for (int j = 0; j < 4; j++) {
    // ======== dense block ========
    ln_k<<<512, 256, 0, stream>>>(tok, m_ln1_g + j * 384, m_ln1_b + j * 384, lnb);
    repack_k<<<1728, 256, 0, stream>>>(m_qw + j * 147456, m_kw + j * 147456, m_vw + j * 147456, wrep);
    {  // fused QKV: [2048,384] x [384,1152]
      GemmP p = mk(lnb, wrep, nullptr, qkv, 2048, 1152, 384, 384, 1152, 1, 1152);
      run_gemm(stream, 0, p, 18, 32, 1);
    }
    {  // scores = q k^T / 8 per (b,h): M=N=512, K=64
      GemmP p = mk(qkv, qkv + 384, nullptr, scores, 512, 512, 64, 1152, 1, 1152, 512);
      p.ZH = 6; p.aSb = 589824; p.aSh = 64; p.bSb = 589824; p.bSh = 64;
      p.cSb = 1572864; p.cSh = 262144; p.scale = 0.125f;
      run_gemm(stream, 4, p, 8, 8, 24);
    }
    softmax_k<<<12288, 256, 0, stream>>>(scores);
    {  // out = A v per (b,h): M=512, N=64, K=512
      GemmP p = mk(scores, qkv + 768, nullptr, attno, 512, 64, 512, 512, 1152, 1, 384);
      p.ZH = 6; p.aSb = 1572864; p.aSh = 262144; p.bSb = 589824; p.bSh = 64;
      p.cSb = 196608; p.cSh = 64;
      run_gemm(stream, 0, p, 1, 8, 24);
    }
    {  // proj + residual into tok
      GemmP p = mk(attno, m_proj_w + j * 147456, m_proj_b + j * 384, tok, 2048, 384, 384, 384, 384, 1, 384);
      run_gemm(stream, 2, p, 6, 32, 1);
    }
    ln_k<<<512, 256, 0, stream>>>(tok, m_ln2_g + j * 384, m_ln2_b + j * 384, lnb);
    {  // FFN1 + relu
      GemmP p = mk(lnb, m_w1 + j * 589824, m_b1 + j * 1536, ffnh, 2048, 1536, 384, 384, 1536, 1, 1536);
      run_gemm(stream, 3, p, 24, 32, 1);
    }
    {  // FFN2 + residual
      GemmP p = mk(ffnh, m_w2 + j * 589824, m_b2 + j * 384, tok, 2048, 384, 1536, 1536, 384, 1, 384);
      run_gemm(stream, 2, p, 6, 32, 1);
    }

    // ======== shifted-window block ========
    ln_k<<<512, 256, 0, stream>>>(tok, s_ln1_g + j * 384, s_ln1_b + j * 384, lnb);
    {
      GemmP p = mk(lnb, s_qkv_w + j * 442368, s_qkv_b + j * 1152, qkv, 2048, 1152, 384, 384, 1152, 1, 1152);
      run_gemm(stream, 0, p, 18, 32, 1);
    }
    swin_k<<<1536, 64, 0, stream>>>(qkv, attno);
    {
      GemmP p = mk(attno, s_proj_w + j * 147456, s_proj_b + j * 384, tok, 2048, 384, 384, 384, 384, 1, 384);
      run_gemm(stream, 2, p, 6, 32, 1);
    }
    ln_k<<<512, 256, 0, stream>>>(tok, s_ln2_g + j * 384, s_ln2_b + j * 384, lnb);
    {
      GemmP p = mk(lnb, s_w1 + j * 589824, s_b1 + j * 1536, ffnh, 2048, 1536, 384, 384, 1536, 1, 1536);
      run_gemm(stream, 3, p, 24, 32, 1);
    }
    {
      GemmP p = mk(ffnh, s_w2 + j * 589824, s_b2 + j * 384, tok, 2048, 384, 1536, 1536, 384, 1, 384);
      run_gemm(stream, 2, p, 6, 32, 1);
    }
  }

  // ---- decoder ----
  {  // deconv1 (all 8 kernel positions via grid.z) + bn1 + relu, scatter to y1 token-major
    GemmP p = mk(tok, d1_w, d1_b, y1, 2048, 384, 384, 384, 3072, 8, 384);
    p.ZH = 8; p.bSh = 1;
    p.e1 = bn1_g; p.e2 = bn1_b; p.e3 = bn1_m; p.e4 = bn1_v;
    run_gemm(stream, 5, p, 6, 32, 8);
  }
  for (int ijk = 0; ijk < 8; ijk++) {
    {  // deconv2 position ijk + bn2 + relu -> out2 [16384,384]
      GemmP p = mk(y1, d2_w + ijk, d2_b, out2, 16384, 384, 384, 384, 3072, 8, 384);
      p.e1 = bn2_g; p.e2 = bn2_b; p.e3 = bn2_m; p.e4 = bn2_v;
      run_gemm(stream, 6, p, 6, 256, 1);
    }
    contract_k<<<1024, 256, 0, stream>>>(out2, out_w, out_b, out, ijk);
  }
}

// Round 4
// 1279.319 us; speedup vs baseline: 2.8739x; 2.8739x over previous
//
#include <hip/hip_runtime.h>
#include <hip/hip_bf16.h>

// ---------------------------------------------------------------------------
// TokenPoseWithShiftedWindow — bf16 MFMA implementation.
// All GEMMs: BM=128 BN=64 BK=64, 4 waves, mfma_f32_16x16x32_bf16,
// global_load_lds(16B) staging with XOR-source-swizzle, fp32 accum/epilogue.
// Residual stream kept fp32; inter-GEMM activations bf16.
// ---------------------------------------------------------------------------

typedef unsigned short u16;
typedef __bf16 bf16x8 __attribute__((ext_vector_type(8)));
typedef float f32x4 __attribute__((ext_vector_type(4)));

__device__ __forceinline__ u16 f2bf(float f) {
  unsigned u = __builtin_bit_cast(unsigned, f);
  return (u16)((u + 0x7FFFu + ((u >> 16) & 1u)) >> 16);
}
__device__ __forceinline__ float bf2f(u16 b) {
  unsigned u = ((unsigned)b) << 16;
  return __builtin_bit_cast(float, u);
}

#define GLOAD_LDS16(g, l)                                                      \
  __builtin_amdgcn_global_load_lds(                                            \
      (const __attribute__((address_space(1))) unsigned int*)(const void*)(g), \
      (__attribute__((address_space(3))) unsigned int*)(void*)(l), 16, 0, 0)

struct MmP {
  const u16* A;   // bf16 [M][K], row stride lda
  const u16* Bt;  // bf16 [N][K], row stride ldb (B transposed)
  const float* bias;
  void* C;        // f32 or bf16 depending on MODE
  const float* e1; const float* e2; const float* e3; const float* e4;
  int K, ZH, lda, ldb, ldc;
  long aSb, aSh, bSb, bSh, cSb, cSh;
  float scale;
};

// MODE: 0 = bf16 store (+bias)            (qkv, attn-out)
//       1 = f32 +bias +pos_emb            (patch embed -> tok)
//       2 = f32 residual += (+bias)       (proj, ffn2 -> tok)
//       3 = bf16 relu(+bias)              (ffn1 -> ffnh)
//       4 = bf16 scale-store              (qk^t scores)
//       5 = bf16 bn-relu deconv1 scatter  (-> y1 token-major)
//       6 = bf16 bn-relu store            (deconv2 -> out2)
template<int MODE>
__global__ __launch_bounds__(256) void mfma_gemm(MmP p) {
  const int z = blockIdx.z;
  const int zb = z / p.ZH, zh = z - zb * p.ZH;
  const u16* A  = p.A  + zb * p.aSb + zh * p.aSh;
  const u16* Bt = p.Bt + zb * p.bSb + zh * p.bSh;
  const int m0 = blockIdx.y * 128, n0 = blockIdx.x * 64;

  __shared__ u16 As[128 * 64];  // [row][8 chunks of 8 bf16], source-swizzled
  __shared__ u16 Bs[64 * 64];

  const int tid = threadIdx.x;
  const int wid = tid >> 6, lane = tid & 63;
  const int wm = (wid >> 1) * 64, wn = (wid & 1) * 32;
  const int lr = lane & 15, lg = lane >> 4;

  f32x4 acc[4][2];
  #pragma unroll
  for (int i = 0; i < 4; i++)
    #pragma unroll
    for (int j = 0; j < 2; j++) acc[i][j] = (f32x4){0.f, 0.f, 0.f, 0.f};

  const int nKT = p.K >> 6;
  for (int kt = 0; kt < nKT; ++kt) {
    if (kt) __syncthreads();
    // stage A: 1024 16B chunks (4/thread); LDS linear, global col XOR-swizzled
    #pragma unroll
    for (int i = 0; i < 4; i++) {
      int c = (i * 4 + wid) * 64 + lane;
      int row = c >> 3, cc = c & 7;
      int gk = ((cc ^ (row & 7)) << 3) + (kt << 6);
      GLOAD_LDS16(A + (long)(m0 + row) * p.lda + gk, As + c * 8);
    }
    // stage B: 512 chunks (2/thread)
    #pragma unroll
    for (int i = 0; i < 2; i++) {
      int c = (i * 4 + wid) * 64 + lane;
      int row = c >> 3, cc = c & 7;
      int gk = ((cc ^ (row & 7)) << 3) + (kt << 6);
      GLOAD_LDS16(Bt + (long)(n0 + row) * p.ldb + gk, Bs + c * 8);
    }
    asm volatile("s_waitcnt vmcnt(0)");
    __syncthreads();

    bf16x8 af[4][2], bfr[2][2];
    #pragma unroll
    for (int i = 0; i < 4; i++)
      #pragma unroll
      for (int ks = 0; ks < 2; ks++) {
        int row = wm + i * 16 + lr;
        int j = ks * 4 + lg;
        af[i][ks] = *(const bf16x8*)(As + (row * 8 + (j ^ (row & 7))) * 8);
      }
    #pragma unroll
    for (int jn = 0; jn < 2; jn++)
      #pragma unroll
      for (int ks = 0; ks < 2; ks++) {
        int row = wn + jn * 16 + lr;
        int j = ks * 4 + lg;
        bfr[jn][ks] = *(const bf16x8*)(Bs + (row * 8 + (j ^ (row & 7))) * 8);
      }
    #pragma unroll
    for (int i = 0; i < 4; i++)
      #pragma unroll
      for (int jn = 0; jn < 2; jn++)
        #pragma unroll
        for (int ks = 0; ks < 2; ks++)
          acc[i][jn] = __builtin_amdgcn_mfma_f32_16x16x32_bf16(
              af[i][ks], bfr[jn][ks], acc[i][jn], 0, 0, 0);
  }

  // epilogue; C/D layout: col = lane&15, row = (lane>>4)*4 + r
  const long coff = zb * p.cSb + zh * p.cSh;
  #pragma unroll
  for (int i = 0; i < 4; i++) {
    const int rowb = m0 + wm + i * 16 + lg * 4;
    #pragma unroll
    for (int jn = 0; jn < 2; jn++) {
      const int col = n0 + wn + jn * 16 + lr;
      const float bv = p.bias ? p.bias[col] : 0.f;
      #pragma unroll
      for (int r = 0; r < 4; r++) {
        const int row = rowb + r;
        const float v = acc[i][jn][r];
        if constexpr (MODE == 0) {
          ((u16*)p.C)[coff + (long)row * p.ldc + col] = f2bf(v + bv);
        } else if constexpr (MODE == 1) {
          ((float*)p.C)[coff + (long)row * p.ldc + col] =
              v + bv + p.e1[(long)(row & 511) * 384 + col];
        } else if constexpr (MODE == 2) {
          ((float*)p.C)[coff + (long)row * p.ldc + col] += v + bv;
        } else if constexpr (MODE == 3) {
          ((u16*)p.C)[coff + (long)row * p.ldc + col] = f2bf(fmaxf(v + bv, 0.f));
        } else if constexpr (MODE == 4) {
          ((u16*)p.C)[coff + (long)row * p.ldc + col] = f2bf(v * p.scale);
        } else if constexpr (MODE == 5) {
          float raw = v + bv;
          float val = fmaxf((raw - p.e3[col]) * rsqrtf(p.e4[col] + 1e-5f) * p.e1[col] + p.e2[col], 0.f);
          int b = row >> 9, hwd = row & 511;
          int h = hwd >> 6, w = (hwd >> 3) & 7, d = hwd & 7;
          int i_ = zh >> 2, j_ = (zh >> 1) & 1, k_ = zh & 1;
          long tokn = (long)b * 4096 + (2 * h + i_) * 256 + (2 * w + j_) * 16 + (2 * d + k_);
          ((u16*)p.C)[tokn * 384 + col] = f2bf(val);
        } else if constexpr (MODE == 6) {
          float raw = v + bv;
          float val = fmaxf((raw - p.e3[col]) * rsqrtf(p.e4[col] + 1e-5f) * p.e1[col] + p.e2[col], 0.f);
          ((u16*)p.C)[(long)row * p.ldc + col] = f2bf(val);
        }
      }
    }
  }
}

// ---------------- aux kernels ----------------

// LayerNorm over C=384; fp32 in, bf16 out. 1 wave/row, 4 rows/block.
__global__ __launch_bounds__(256) void ln_k(const float* __restrict__ x, const float* __restrict__ g,
                                            const float* __restrict__ b, u16* __restrict__ y) {
  const int row = (blockIdx.x << 2) + (threadIdx.x >> 6);
  const int lane = threadIdx.x & 63;
  const float* xr = x + (long)row * 384;
  float v[6]; float s = 0.f;
  #pragma unroll
  for (int i = 0; i < 6; i++) { v[i] = xr[lane + (i << 6)]; s += v[i]; }
  #pragma unroll
  for (int o = 32; o >= 1; o >>= 1) s += __shfl_xor(s, o);
  const float mean = s * (1.f / 384.f);
  float q = 0.f;
  #pragma unroll
  for (int i = 0; i < 6; i++) { float dd = v[i] - mean; q += dd * dd; }
  #pragma unroll
  for (int o = 32; o >= 1; o >>= 1) q += __shfl_xor(q, o);
  const float rstd = rsqrtf(q * (1.f / 384.f) + 1e-5f);
  u16* yr = y + (long)row * 384;
  #pragma unroll
  for (int i = 0; i < 6; i++) {
    int c = lane + (i << 6);
    yr[c] = f2bf((v[i] - mean) * rstd * g[c] + b[c]);
  }
}

// In-place row softmax over 512 bf16 scores (block-local row => safe in-place).
__global__ __launch_bounds__(256) void softmax_k(u16* __restrict__ s) {
  u16* row = s + (long)blockIdx.x * 512;
  const int tid = threadIdx.x;
  float v0 = bf2f(row[tid]), v1 = bf2f(row[tid + 256]);
  float m = fmaxf(v0, v1);
  #pragma unroll
  for (int o = 32; o >= 1; o >>= 1) m = fmaxf(m, __shfl_xor(m, o));
  __shared__ float r1[4], r2[4];
  if ((tid & 63) == 0) r1[tid >> 6] = m;
  __syncthreads();
  m = fmaxf(fmaxf(r1[0], r1[1]), fmaxf(r1[2], r1[3]));
  float e0 = __expf(v0 - m), e1 = __expf(v1 - m);
  float sm = e0 + e1;
  #pragma unroll
  for (int o = 32; o >= 1; o >>= 1) sm += __shfl_xor(sm, o);
  if ((tid & 63) == 0) r2[tid >> 6] = sm;
  __syncthreads();
  const float inv = 1.f / (r2[0] + r2[1] + r2[2] + r2[3]);
  row[tid] = f2bf(e0 * inv);
  row[tid + 256] = f2bf(e1 * inv);
}

// Shifted-window attention on bf16 qkv; bf16 out. 1 block(64) per (b,win,head).
__global__ __launch_bounds__(64) void swin_k(const u16* __restrict__ qkv, u16* __restrict__ attno) {
  const int blk = blockIdx.x;
  const int h = blk % 6; const int bw = blk / 6;
  const int b = bw >> 6, win = bw & 63;
  const int wh = win >> 4, ww = (win >> 2) & 3, wd = win & 3;
  const int lane = threadIdx.x;
  __shared__ float qs[8][68], ks[8][68], vs[8][68], attw[8][8];
  __shared__ int ntok[8];
  if (lane < 8) {
    int i = lane >> 2, j = (lane >> 1) & 1, k = lane & 1;
    int oh = (2 * wh + i + 1) & 7, ow = (2 * ww + j + 1) & 7, od = (2 * wd + k + 1) & 7;
    ntok[lane] = oh * 64 + ow * 8 + od;
  }
  __syncthreads();
  #pragma unroll
  for (int t = 0; t < 8; t++) {
    long base = ((long)b * 512 + ntok[t]) * 1152 + h * 64 + lane;
    qs[t][lane] = bf2f(qkv[base]);
    ks[t][lane] = bf2f(qkv[base + 384]);
    vs[t][lane] = bf2f(qkv[base + 768]);
  }
  __syncthreads();
  const int tq = lane >> 3, tm = lane & 7;
  float sc = 0.f;
  #pragma unroll 16
  for (int d = 0; d < 64; d++) sc += qs[tq][d] * ks[tm][d];
  sc *= 0.125f;
  float mx = sc;
  mx = fmaxf(mx, __shfl_xor(mx, 4));
  mx = fmaxf(mx, __shfl_xor(mx, 2));
  mx = fmaxf(mx, __shfl_xor(mx, 1));
  float e = __expf(sc - mx);
  float sm = e;
  sm += __shfl_xor(sm, 4); sm += __shfl_xor(sm, 2); sm += __shfl_xor(sm, 1);
  attw[tq][tm] = e / sm;
  __syncthreads();
  #pragma unroll
  for (int t = 0; t < 8; t++) {
    float o = 0.f;
    #pragma unroll
    for (int m = 0; m < 8; m++) o += attw[t][m] * vs[m][lane];
    attno[((long)b * 512 + ntok[t]) * 384 + h * 64 + lane] = f2bf(o);
  }
}

// Patch im2col -> bf16 [2048][512]
__global__ __launch_bounds__(256) void im2col_k(const float* __restrict__ x, u16* __restrict__ xp) {
  const int i = blockIdx.x * 256 + threadIdx.x;
  const int l = i & 511; const int m = i >> 9;
  const int b = m >> 9, n = m & 511;
  const int h = n >> 6, w = (n >> 3) & 7, d = n & 7;
  const int pi = l >> 6, pj = (l >> 3) & 7, pk = l & 7;
  xp[i] = f2bf(x[(long)b * 262144 + (long)(h * 8 + pi) * 4096 + (w * 8 + pj) * 64 + (d * 8 + pk)]);
}

// generic fp32 -> bf16 cast
__global__ __launch_bounds__(256) void castw_k(const float* __restrict__ in, u16* __restrict__ out, int n) {
  for (int i = blockIdx.x * 256 + threadIdx.x; i < n; i += gridDim.x * 256)
    out[i] = f2bf(in[i]);
}

// batched transpose+cast: out[z][n][k] = in[z][k][n]
__global__ __launch_bounds__(256) void transpose_w_k(const float* __restrict__ in, u16* __restrict__ out,
                                                     int K, int N) {
  const long total = (long)K * N;
  const long base = (long)blockIdx.z * total;
  for (long idx = blockIdx.x * 256 + threadIdx.x; idx < total; idx += (long)gridDim.x * 256) {
    long n = idx / K, k = idx - n * K;
    out[base + idx] = f2bf(in[base + k * N + n]);
  }
}

// dense per-head qkv weights -> [4][1152][384] bf16 (n = s*384 + h*64 + d, k = c)
__global__ __launch_bounds__(256) void repack_mqkv_k(const float* __restrict__ qw, const float* __restrict__ kw,
                                                     const float* __restrict__ vw, u16* __restrict__ out) {
  const int j = blockIdx.z;
  const float* srcs[3] = {qw + j * 147456, kw + j * 147456, vw + j * 147456};
  for (int idx = blockIdx.x * 256 + threadIdx.x; idx < 442368; idx += gridDim.x * 256) {
    int r = idx / 384, c = idx - r * 384;
    int s = r / 384;
    int hd = r - s * 384; int h = hd >> 6, d = hd & 63;
    out[(long)j * 442368 + idx] = f2bf(srcs[s][(h * 384 + c) * 64 + d]);
  }
}

// deconv weights [C][O][2][2][2] -> [8][O][C] bf16
__global__ __launch_bounds__(256) void repack_dw_k(const float* __restrict__ in, u16* __restrict__ out) {
  for (int idx = blockIdx.x * 256 + threadIdx.x; idx < 1179648; idx += gridDim.x * 256) {
    int ijk = idx / 147456, rem = idx - ijk * 147456;
    int o = rem / 384, c = rem - o * 384;
    out[idx] = f2bf(in[c * 3072 + o * 8 + ijk]);
  }
}

// v-part of qkv -> vT [b*6+h][64][512] bf16
__global__ __launch_bounds__(256) void vT_k(const u16* __restrict__ qkv, u16* __restrict__ vT) {
  for (int idx = blockIdx.x * 256 + threadIdx.x; idx < 786432; idx += gridDim.x * 256) {
    int z = idx >> 15, d = (idx >> 9) & 63, t = idx & 511;
    int b = z / 6, h = z - b * 6;
    vT[idx] = qkv[((long)(b * 512 + t)) * 1152 + 768 + h * 64 + d];
  }
}

// final 1x1 conv over bf16 activations; fp32 out_w; scatter per kernel pos ijk
__global__ __launch_bounds__(256) void contract_k(const u16* __restrict__ act, const float* __restrict__ ow,
                                                  const float* __restrict__ ob, float* __restrict__ out, int ijk) {
  __shared__ __align__(16) float tile[16][388];
  __shared__ __align__(16) float wsh[15][388];
  const int tid = threadIdx.x;
  for (int idx = tid; idx < 15 * 384; idx += 256) {
    int kp = idx / 384, c = idx - kp * 384;
    wsh[kp][c] = ow[idx];
  }
  const long row0 = (long)blockIdx.x << 4;
  for (int idx = tid; idx < 16 * 384; idx += 256) {
    int r = idx / 384, c = idx - r * 384;
    tile[r][c] = bf2f(act[(row0 + r) * 384 + c]);
  }
  __syncthreads();
  const int r = tid >> 4, kp = tid & 15;
  if (kp < 15) {
    float acc = 0.f;
    #pragma unroll 8
    for (int c = 0; c < 384; c += 4) {
      float4 a = *(const float4*)&tile[r][c];
      float4 w = *(const float4*)&wsh[kp][c];
      acc += a.x * w.x + a.y * w.y + a.z * w.z + a.w * w.w;
    }
    const int gm = (int)row0 + r;
    const int b = gm >> 12, h = (gm >> 8) & 15, w = (gm >> 4) & 15, d = gm & 15;
    const int i = ijk >> 2, j = (ijk >> 1) & 1, k = ijk & 1;
    const long o = ((long)(b * 15 + kp) << 15) + (2 * h + i) * 1024 + (2 * w + j) * 32 + (2 * d + k);
    out[o] = acc + ob[kp];
  }
}

// ---------------------------------------------------------------------------

static MmP mk(const u16* A, const u16* Bt, const float* bias, void* C,
              int K, int lda, int ldb, int ldc) {
  MmP p{};
  p.A = A; p.Bt = Bt; p.bias = bias; p.C = C;
  p.e1 = p.e2 = p.e3 = p.e4 = nullptr;
  p.K = K; p.ZH = 1; p.lda = lda; p.ldb = ldb; p.ldc = ldc;
  p.aSb = p.aSh = p.bSb = p.bSh = p.cSb = p.cSh = 0;
  p.scale = 1.f;
  return p;
}

static void run_mm(hipStream_t st, int mode, const MmP& p, int gx, int gy, int gz) {
  dim3 g(gx, gy, gz), blk(256, 1, 1);
  switch (mode) {
    case 0: mfma_gemm<0><<<g, blk, 0, st>>>(p); break;
    case 1: mfma_gemm<1><<<g, blk, 0, st>>>(p); break;
    case 2: mfma_gemm<2><<<g, blk, 0, st>>>(p); break;
    case 3: mfma_gemm<3><<<g, blk, 0, st>>>(p); break;
    case 4: mfma_gemm<4><<<g, blk, 0, st>>>(p); break;
    case 5: mfma_gemm<5><<<g, blk, 0, st>>>(p); break;
    case 6: mfma_gemm<6><<<g, blk, 0, st>>>(p); break;
  }
}

extern "C" void kernel_launch(void* const* d_in, const int* in_sizes, int n_in,
                              void* d_out, int out_size, void* d_ws, size_t ws_size,
                              hipStream_t stream) {
  (void)in_sizes; (void)n_in; (void)out_size; (void)ws_size;
  const float* x        = (const float*)d_in[0];
  const float* patch_w  = (const float*)d_in[1];
  const float* patch_b  = (const float*)d_in[2];
  const float* pos_emb  = (const float*)d_in[3];
  const float* m_ln1_g  = (const float*)d_in[4];
  const float* m_ln1_b  = (const float*)d_in[5];
  const float* m_qw     = (const float*)d_in[6];
  const float* m_kw     = (const float*)d_in[7];
  const float* m_vw     = (const float*)d_in[8];
  const float* m_proj_w = (const float*)d_in[9];
  const float* m_proj_b = (const float*)d_in[10];
  const float* m_ln2_g  = (const float*)d_in[11];
  const float* m_ln2_b  = (const float*)d_in[12];
  const float* m_w1     = (const float*)d_in[13];
  const float* m_b1     = (const float*)d_in[14];
  const float* m_w2     = (const float*)d_in[15];
  const float* m_b2     = (const float*)d_in[16];
  const float* s_ln1_g  = (const float*)d_in[17];
  const float* s_ln1_b  = (const float*)d_in[18];
  const float* s_qkv_w  = (const float*)d_in[19];
  const float* s_qkv_b  = (const float*)d_in[20];
  const float* s_proj_w = (const float*)d_in[21];
  const float* s_proj_b = (const float*)d_in[22];
  const float* s_ln2_g  = (const float*)d_in[23];
  const float* s_ln2_b  = (const float*)d_in[24];
  const float* s_w1     = (const float*)d_in[25];
  const float* s_b1     = (const float*)d_in[26];
  const float* s_w2     = (const float*)d_in[27];
  const float* s_b2     = (const float*)d_in[28];
  const float* d1_w     = (const float*)d_in[29];
  const float* d1_b     = (const float*)d_in[30];
  const float* bn1_g    = (const float*)d_in[31];
  const float* bn1_b    = (const float*)d_in[32];
  const float* bn1_m    = (const float*)d_in[33];
  const float* bn1_v    = (const float*)d_in[34];
  const float* d2_w     = (const float*)d_in[35];
  const float* d2_b     = (const float*)d_in[36];
  const float* bn2_g    = (const float*)d_in[37];
  const float* bn2_b    = (const float*)d_in[38];
  const float* bn2_m    = (const float*)d_in[39];
  const float* bn2_v    = (const float*)d_in[40];
  const float* out_w    = (const float*)d_in[41];
  const float* out_b    = (const float*)d_in[42];
  float* out = (float*)d_out;

  // ---- workspace arena (all offsets fixed; ~65 MB) ----
  char* wsp = (char*)d_ws;
  auto alloc = [&](size_t bytes) { void* p = wsp; wsp += (bytes + 255) & ~(size_t)255; return p; };
  float* tok    = (float*)alloc(786432 * 4);
  u16* wqkv_m   = (u16*)alloc(1769472 * 2);
  u16* wqkv_s   = (u16*)alloc(1769472 * 2);
  u16* wproj_m  = (u16*)alloc(589824 * 2);
  u16* wproj_s  = (u16*)alloc(589824 * 2);
  u16* w1m      = (u16*)alloc(2359296 * 2);
  u16* w1s      = (u16*)alloc(2359296 * 2);
  u16* w2m      = (u16*)alloc(2359296 * 2);
  u16* w2s      = (u16*)alloc(2359296 * 2);
  u16* wpatch   = (u16*)alloc(196608 * 2);
  u16* wd1      = (u16*)alloc(1179648 * 2);
  u16* wd2      = (u16*)alloc(1179648 * 2);
  u16* lnb      = (u16*)alloc(786432 * 2);
  u16* qkvb     = (u16*)alloc(2359296 * 2);   // qkvb..ffnhb contiguous 12.6MB (aliased by out2b)
  u16* attnob   = (u16*)alloc(786432 * 2);
  u16* ffnhb    = (u16*)alloc(3145728 * 2);
  u16* scoresb  = (u16*)alloc(6291456 * 2);   // 24x512x512; aliased by xp (early) / y1b (late)
  u16* vTb      = (u16*)alloc(786432 * 2);    // aliased by tokb (late)
  u16* xpb   = scoresb;  // [2048][512] used only before first attention
  u16* y1b   = scoresb;  // decoder: token-major [B,16,16,16,C]
  u16* out2b = qkvb;     // decoder: [16384][384]
  u16* tokb  = vTb;

  // ---- weight repack (bf16, B^T layout) ----
  castw_k<<<256, 256, 0, stream>>>(patch_w, wpatch, 196608);
  repack_mqkv_k<<<dim3(128, 1, 4), 256, 0, stream>>>(m_qw, m_kw, m_vw, wqkv_m);
  transpose_w_k<<<dim3(256, 1, 4), 256, 0, stream>>>(s_qkv_w, wqkv_s, 384, 1152);
  transpose_w_k<<<dim3(128, 1, 4), 256, 0, stream>>>(m_proj_w, wproj_m, 384, 384);
  transpose_w_k<<<dim3(128, 1, 4), 256, 0, stream>>>(s_proj_w, wproj_s, 384, 384);
  transpose_w_k<<<dim3(256, 1, 4), 256, 0, stream>>>(m_w1, w1m, 384, 1536);
  transpose_w_k<<<dim3(256, 1, 4), 256, 0, stream>>>(s_w1, w1s, 384, 1536);
  transpose_w_k<<<dim3(256, 1, 4), 256, 0, stream>>>(m_w2, w2m, 1536, 384);
  transpose_w_k<<<dim3(256, 1, 4), 256, 0, stream>>>(s_w2, w2s, 1536, 384);
  repack_dw_k<<<512, 256, 0, stream>>>(d1_w, wd1);
  repack_dw_k<<<512, 256, 0, stream>>>(d2_w, wd2);

  // ---- patch embedding + pos_emb -> tok (fp32) ----
  im2col_k<<<4096, 256, 0, stream>>>(x, xpb);
  {
    MmP p = mk(xpb, wpatch, patch_b, tok, 512, 512, 512, 384);
    p.e1 = pos_emb;
    run_mm(stream, 1, p, 6, 16, 1);
  }

  for (int j = 0; j < 4; j++) {
    // ======== dense block ========
    ln_k<<<512, 256, 0, stream>>>(tok, m_ln1_g + j * 384, m_ln1_b + j * 384, lnb);
    {  // QKV (no bias): [2048,384]x[384,1152] -> qkvb bf16
      MmP p = mk(lnb, wqkv_m + (long)j * 442368, nullptr, qkvb, 384, 384, 384, 1152);
      run_mm(stream, 0, p, 18, 16, 1);
    }
    vT_k<<<512, 256, 0, stream>>>(qkvb, vTb);
    {  // scores = q k^T / 8 per (b,h) -> bf16
      MmP p = mk(qkvb, qkvb + 384, nullptr, scoresb, 64, 1152, 1152, 512);
      p.ZH = 6; p.aSb = 589824; p.aSh = 64; p.bSb = 589824; p.bSh = 64;
      p.cSb = 1572864; p.cSh = 262144; p.scale = 0.125f;
      run_mm(stream, 4, p, 8, 4, 24);
    }
    softmax_k<<<12288, 256, 0, stream>>>(scoresb);
    {  // attno = P vT^T per (b,h): M=512 N=64 K=512
      MmP p = mk(scoresb, vTb, nullptr, attnob, 512, 512, 512, 384);
      p.ZH = 6; p.aSb = 1572864; p.aSh = 262144; p.bSb = 196608; p.bSh = 32768;
      p.cSb = 196608; p.cSh = 64;
      run_mm(stream, 0, p, 1, 4, 24);
    }
    {  // proj + residual -> tok fp32
      MmP p = mk(attnob, wproj_m + (long)j * 147456, m_proj_b + j * 384, tok, 384, 384, 384, 384);
      run_mm(stream, 2, p, 6, 16, 1);
    }
    ln_k<<<512, 256, 0, stream>>>(tok, m_ln2_g + j * 384, m_ln2_b + j * 384, lnb);
    {  // FFN1 relu -> ffnhb bf16
      MmP p = mk(lnb, w1m + (long)j * 589824, m_b1 + j * 1536, ffnhb, 384, 384, 384, 1536);
      run_mm(stream, 3, p, 24, 16, 1);
    }
    {  // FFN2 + residual -> tok
      MmP p = mk(ffnhb, w2m + (long)j * 589824, m_b2 + j * 384, tok, 1536, 1536, 1536, 384);
      run_mm(stream, 2, p, 6, 16, 1);
    }

    // ======== shifted-window block ========
    ln_k<<<512, 256, 0, stream>>>(tok, s_ln1_g + j * 384, s_ln1_b + j * 384, lnb);
    {
      MmP p = mk(lnb, wqkv_s + (long)j * 442368, s_qkv_b + j * 1152, qkvb, 384, 384, 384, 1152);
      run_mm(stream, 0, p, 18, 16, 1);
    }
    swin_k<<<1536, 64, 0, stream>>>(qkvb, attnob);
    {
      MmP p = mk(attnob, wproj_s + (long)j * 147456, s_proj_b + j * 384, tok, 384, 384, 384, 384);
      run_mm(stream, 2, p, 6, 16, 1);
    }
    ln_k<<<512, 256, 0, stream>>>(tok, s_ln2_g + j * 384, s_ln2_b + j * 384, lnb);
    {
      MmP p = mk(lnb, w1s + (long)j * 589824, s_b1 + j * 1536, ffnhb, 384, 384, 384, 1536);
      run_mm(stream, 3, p, 24, 16, 1);
    }
    {
      MmP p = mk(ffnhb, w2s + (long)j * 589824, s_b2 + j * 384, tok, 1536, 1536, 1536, 384);
      run_mm(stream, 2, p, 6, 16, 1);
    }
  }

  // ---- decoder ----
  castw_k<<<768, 256, 0, stream>>>(tok, tokb, 786432);
  {  // deconv1 all 8 positions (grid.z) + bn1-relu -> y1b bf16 token-major
    MmP p = mk(tokb, wd1, d1_b, y1b, 384, 384, 384, 384);
    p.ZH = 8; p.bSh = 147456;
    p.e1 = bn1_g; p.e2 = bn1_b; p.e3 = bn1_m; p.e4 = bn1_v;
    run_mm(stream, 5, p, 6, 16, 8);
  }
  for (int ijk = 0; ijk < 8; ijk++) {
    {  // deconv2 position ijk + bn2-relu -> out2b bf16 [16384][384]
      MmP p = mk(y1b, wd2 + (long)ijk * 147456, d2_b, out2b, 384, 384, 384, 384);
      p.e1 = bn2_g; p.e2 = bn2_b; p.e3 = bn2_m; p.e4 = bn2_v;
      run_mm(stream, 6, p, 6, 128, 1);
    }
    contract_k<<<1024, 256, 0, stream>>>(out2b, out_w, out_b, out, ijk);
  }
}

// Round 5
// 1138.156 us; speedup vs baseline: 3.2303x; 1.1240x over previous
//
#include <hip/hip_runtime.h>
#include <hip/hip_bf16.h>

// ---------------------------------------------------------------------------
// TokenPoseWithShiftedWindow — bf16 MFMA, round 5.
// GEMM: 2-phase double-buffered LDS pipeline (T3 minimum), BM in {128,64},
// BN=64, BK=64, 4 waves, mfma_f32_16x16x32_bf16, global_load_lds(16B) with
// XOR-source-swizzle. Fused scores+softmax kernel for dense attention.
// ---------------------------------------------------------------------------

typedef unsigned short u16;
typedef __bf16 bf16x8 __attribute__((ext_vector_type(8)));
typedef float f32x4 __attribute__((ext_vector_type(4)));

__device__ __forceinline__ u16 f2bf(float f) {
  unsigned u = __builtin_bit_cast(unsigned, f);
  return (u16)((u + 0x7FFFu + ((u >> 16) & 1u)) >> 16);
}
__device__ __forceinline__ float bf2f(u16 b) {
  unsigned u = ((unsigned)b) << 16;
  return __builtin_bit_cast(float, u);
}

#define GLOAD_LDS16(g, l)                                                      \
  __builtin_amdgcn_global_load_lds(                                            \
      (const __attribute__((address_space(1))) unsigned int*)(const void*)(g), \
      (__attribute__((address_space(3))) unsigned int*)(void*)(l), 16, 0, 0)

struct MmP {
  const u16* A;   // bf16 [M][K], row stride lda
  const u16* Bt;  // bf16 [N][K], row stride ldb (B transposed)
  const float* bias;
  void* C;
  const float* e1; const float* e2; const float* e3; const float* e4;
  int K, ZH, lda, ldb, ldc;
  long aSb, aSh, bSb, bSh, cSb, cSh;
};

// MODE: 0 = bf16 store (+bias)            (qkv, attn-out)
//       1 = f32 +bias +pos_emb            (patch embed -> tok)
//       2 = f32 residual += (+bias)       (proj, ffn2 -> tok)
//       3 = bf16 relu(+bias)              (ffn1 -> ffnh)
//       5 = bf16 bn-relu deconv1 scatter  (-> y1 token-major)
//       6 = bf16 bn-relu store            (deconv2 -> out2)
template<int MODE, int BM>
__global__ __launch_bounds__(256) void mfma_gemm(MmP p) {
  const int z = blockIdx.z;
  const int zb = z / p.ZH, zh = z - zb * p.ZH;
  const u16* A  = p.A  + zb * p.aSb + zh * p.aSh;
  const u16* Bt = p.Bt + zb * p.bSb + zh * p.bSh;
  const int m0 = blockIdx.y * BM, n0 = blockIdx.x * 64;

  __shared__ u16 As[2][BM * 64];
  __shared__ u16 Bs[2][64 * 64];

  const int tid = threadIdx.x;
  const int wid = tid >> 6, lane = tid & 63;
  constexpr int MI = BM / 32;                 // row-frags per wave: 4 or 2
  const int wm = (wid >> 1) * (BM / 2), wn = (wid & 1) * 32;
  const int lr = lane & 15, lg = lane >> 4;
  constexpr int ACH = BM / 32;                // A chunks per thread (16B each)

  f32x4 acc[MI][2];
  #pragma unroll
  for (int i = 0; i < MI; i++)
    #pragma unroll
    for (int j = 0; j < 2; j++) acc[i][j] = (f32x4){0.f, 0.f, 0.f, 0.f};

  auto stage = [&](int buf, int kt) {
    #pragma unroll
    for (int i = 0; i < ACH; i++) {
      int c = i * 256 + tid;
      int row = c >> 3, cc = c & 7;
      int gk = ((cc ^ (row & 7)) << 3) + (kt << 6);
      GLOAD_LDS16(A + (long)(m0 + row) * p.lda + gk, As[buf] + c * 8);
    }
    #pragma unroll
    for (int i = 0; i < 2; i++) {
      int c = i * 256 + tid;
      int row = c >> 3, cc = c & 7;
      int gk = ((cc ^ (row & 7)) << 3) + (kt << 6);
      GLOAD_LDS16(Bt + (long)(n0 + row) * p.ldb + gk, Bs[buf] + c * 8);
    }
  };

  const int nKT = p.K >> 6;
  stage(0, 0);
  asm volatile("s_waitcnt vmcnt(0)");
  __syncthreads();

  int cur = 0;
  for (int kt = 0; kt < nKT; ++kt) {
    const bool more = (kt + 1 < nKT);
    if (more) stage(cur ^ 1, kt + 1);

    bf16x8 af[MI][2], bfr[2][2];
    #pragma unroll
    for (int i = 0; i < MI; i++)
      #pragma unroll
      for (int ks = 0; ks < 2; ks++) {
        int row = wm + i * 16 + lr;
        int j = ks * 4 + lg;
        af[i][ks] = *(const bf16x8*)(As[cur] + (row * 8 + (j ^ (row & 7))) * 8);
      }
    #pragma unroll
    for (int jn = 0; jn < 2; jn++)
      #pragma unroll
      for (int ks = 0; ks < 2; ks++) {
        int row = wn + jn * 16 + lr;
        int j = ks * 4 + lg;
        bfr[jn][ks] = *(const bf16x8*)(Bs[cur] + (row * 8 + (j ^ (row & 7))) * 8);
      }
    #pragma unroll
    for (int i = 0; i < MI; i++)
      #pragma unroll
      for (int jn = 0; jn < 2; jn++)
        #pragma unroll
        for (int ks = 0; ks < 2; ks++)
          acc[i][jn] = __builtin_amdgcn_mfma_f32_16x16x32_bf16(
              af[i][ks], bfr[jn][ks], acc[i][jn], 0, 0, 0);

    if (more) {
      asm volatile("s_waitcnt vmcnt(0)");
      __syncthreads();
      cur ^= 1;
    }
  }

  // epilogue; C/D layout: col = lane&15, row = (lane>>4)*4 + r
  const long coff = zb * p.cSb + zh * p.cSh;
  #pragma unroll
  for (int i = 0; i < MI; i++) {
    const int rowb = m0 + wm + i * 16 + lg * 4;
    #pragma unroll
    for (int jn = 0; jn < 2; jn++) {
      const int col = n0 + wn + jn * 16 + lr;
      const float bv = p.bias ? p.bias[col] : 0.f;
      #pragma unroll
      for (int r = 0; r < 4; r++) {
        const int row = rowb + r;
        const float v = acc[i][jn][r];
        if constexpr (MODE == 0) {
          ((u16*)p.C)[coff + (long)row * p.ldc + col] = f2bf(v + bv);
        } else if constexpr (MODE == 1) {
          ((float*)p.C)[coff + (long)row * p.ldc + col] =
              v + bv + p.e1[(long)(row & 511) * 384 + col];
        } else if constexpr (MODE == 2) {
          ((float*)p.C)[coff + (long)row * p.ldc + col] += v + bv;
        } else if constexpr (MODE == 3) {
          ((u16*)p.C)[coff + (long)row * p.ldc + col] = f2bf(fmaxf(v + bv, 0.f));
        } else if constexpr (MODE == 5) {
          float raw = v + bv;
          float val = fmaxf((raw - p.e3[col]) * rsqrtf(p.e4[col] + 1e-5f) * p.e1[col] + p.e2[col], 0.f);
          int b = row >> 9, hwd = row & 511;
          int h = hwd >> 6, w = (hwd >> 3) & 7, d = hwd & 7;
          int i_ = zh >> 2, j_ = (zh >> 1) & 1, k_ = zh & 1;
          long tokn = (long)b * 4096 + (2 * h + i_) * 256 + (2 * w + j_) * 16 + (2 * d + k_);
          ((u16*)p.C)[tokn * 384 + col] = f2bf(val);
        } else if constexpr (MODE == 6) {
          float raw = v + bv;
          float val = fmaxf((raw - p.e3[col]) * rsqrtf(p.e4[col] + 1e-5f) * p.e1[col] + p.e2[col], 0.f);
          ((u16*)p.C)[(long)row * p.ldc + col] = f2bf(val);
        }
      }
    }
  }
}

// Fused scores+softmax: P = softmax(Q K^T / 8) per (b,h). One block per
// (q-tile of 128, bh); 512 threads (8 waves, 16 q-rows each); K in LDS.
__global__ __launch_bounds__(512) void attnsm_k(const u16* __restrict__ qkv, u16* __restrict__ P) {
  const int bh = blockIdx.y;
  const int b = bh / 6, h = bh - b * 6;
  const int qt = blockIdx.x;
  const int tid = threadIdx.x, wid = tid >> 6, lane = tid & 63;
  const int lr = lane & 15, lg = lane >> 4;
  __shared__ u16 Ks[512 * 64];  // 64 KB, chunk-swizzled
  const u16* qbase = qkv + ((long)b * 512) * 1152 + h * 64;

  #pragma unroll
  for (int i = 0; i < 8; i++) {
    int c = i * 512 + tid;
    int t = c >> 3, cc = c & 7;
    int gk = (cc ^ (t & 7)) << 3;
    GLOAD_LDS16(qbase + (long)t * 1152 + 384 + gk, Ks + c * 8);
  }
  const int qrow = qt * 128 + wid * 16 + lr;
  bf16x8 qf[2];
  #pragma unroll
  for (int ks = 0; ks < 2; ks++)
    qf[ks] = *(const bf16x8*)(qbase + (long)qrow * 1152 + (ks * 4 + lg) * 8);
  asm volatile("s_waitcnt vmcnt(0)");
  __syncthreads();

  f32x4 s[32];
  #pragma unroll
  for (int nt = 0; nt < 32; nt++) {
    s[nt] = (f32x4){0.f, 0.f, 0.f, 0.f};
    #pragma unroll
    for (int ks = 0; ks < 2; ks++) {
      int row = nt * 16 + lr;
      int j = ks * 4 + lg;
      bf16x8 kf = *(const bf16x8*)(Ks + (row * 8 + (j ^ (row & 7))) * 8);
      s[nt] = __builtin_amdgcn_mfma_f32_16x16x32_bf16(qf[ks], kf, s[nt], 0, 0, 0);
    }
  }
  float mx[4] = {-1e30f, -1e30f, -1e30f, -1e30f};
  #pragma unroll
  for (int nt = 0; nt < 32; nt++)
    #pragma unroll
    for (int r = 0; r < 4; r++) { s[nt][r] *= 0.125f; mx[r] = fmaxf(mx[r], s[nt][r]); }
  #pragma unroll
  for (int o = 8; o >= 1; o >>= 1)
    #pragma unroll
    for (int r = 0; r < 4; r++) mx[r] = fmaxf(mx[r], __shfl_xor(mx[r], o));
  float sum[4] = {0.f, 0.f, 0.f, 0.f};
  #pragma unroll
  for (int nt = 0; nt < 32; nt++)
    #pragma unroll
    for (int r = 0; r < 4; r++) { float e = __expf(s[nt][r] - mx[r]); s[nt][r] = e; sum[r] += e; }
  #pragma unroll
  for (int o = 8; o >= 1; o >>= 1)
    #pragma unroll
    for (int r = 0; r < 4; r++) sum[r] += __shfl_xor(sum[r], o);
  float inv[4];
  #pragma unroll
  for (int r = 0; r < 4; r++) inv[r] = 1.f / sum[r];

  u16* Pb = P + (long)bh * 262144;
  const int prow0 = qt * 128 + wid * 16 + lg * 4;
  #pragma unroll
  for (int nt = 0; nt < 32; nt++)
    #pragma unroll
    for (int r = 0; r < 4; r++)
      Pb[(long)(prow0 + r) * 512 + nt * 16 + lr] = f2bf(s[nt][r] * inv[r]);
}

// ---------------- aux kernels ----------------

__global__ __launch_bounds__(256) void ln_k(const float* __restrict__ x, const float* __restrict__ g,
                                            const float* __restrict__ b, u16* __restrict__ y) {
  const int row = (blockIdx.x << 2) + (threadIdx.x >> 6);
  const int lane = threadIdx.x & 63;
  const float* xr = x + (long)row * 384;
  float v[6]; float s = 0.f;
  #pragma unroll
  for (int i = 0; i < 6; i++) { v[i] = xr[lane + (i << 6)]; s += v[i]; }
  #pragma unroll
  for (int o = 32; o >= 1; o >>= 1) s += __shfl_xor(s, o);
  const float mean = s * (1.f / 384.f);
  float q = 0.f;
  #pragma unroll
  for (int i = 0; i < 6; i++) { float dd = v[i] - mean; q += dd * dd; }
  #pragma unroll
  for (int o = 32; o >= 1; o >>= 1) q += __shfl_xor(q, o);
  const float rstd = rsqrtf(q * (1.f / 384.f) + 1e-5f);
  u16* yr = y + (long)row * 384;
  #pragma unroll
  for (int i = 0; i < 6; i++) {
    int c = lane + (i << 6);
    yr[c] = f2bf((v[i] - mean) * rstd * g[c] + b[c]);
  }
}

__global__ __launch_bounds__(64) void swin_k(const u16* __restrict__ qkv, u16* __restrict__ attno) {
  const int blk = blockIdx.x;
  const int h = blk % 6; const int bw = blk / 6;
  const int b = bw >> 6, win = bw & 63;
  const int wh = win >> 4, ww = (win >> 2) & 3, wd = win & 3;
  const int lane = threadIdx.x;
  __shared__ float qs[8][68], ks[8][68], vs[8][68], attw[8][8];
  __shared__ int ntok[8];
  if (lane < 8) {
    int i = lane >> 2, j = (lane >> 1) & 1, k = lane & 1;
    int oh = (2 * wh + i + 1) & 7, ow = (2 * ww + j + 1) & 7, od = (2 * wd + k + 1) & 7;
    ntok[lane] = oh * 64 + ow * 8 + od;
  }
  __syncthreads();
  #pragma unroll
  for (int t = 0; t < 8; t++) {
    long base = ((long)b * 512 + ntok[t]) * 1152 + h * 64 + lane;
    qs[t][lane] = bf2f(qkv[base]);
    ks[t][lane] = bf2f(qkv[base + 384]);
    vs[t][lane] = bf2f(qkv[base + 768]);
  }
  __syncthreads();
  const int tq = lane >> 3, tm = lane & 7;
  float sc = 0.f;
  #pragma unroll 16
  for (int d = 0; d < 64; d++) sc += qs[tq][d] * ks[tm][d];
  sc *= 0.125f;
  float mx = sc;
  mx = fmaxf(mx, __shfl_xor(mx, 4));
  mx = fmaxf(mx, __shfl_xor(mx, 2));
  mx = fmaxf(mx, __shfl_xor(mx, 1));
  float e = __expf(sc - mx);
  float sm = e;
  sm += __shfl_xor(sm, 4); sm += __shfl_xor(sm, 2); sm += __shfl_xor(sm, 1);
  attw[tq][tm] = e / sm;
  __syncthreads();
  #pragma unroll
  for (int t = 0; t < 8; t++) {
    float o = 0.f;
    #pragma unroll
    for (int m = 0; m < 8; m++) o += attw[t][m] * vs[m][lane];
    attno[((long)b * 512 + ntok[t]) * 384 + h * 64 + lane] = f2bf(o);
  }
}

__global__ __launch_bounds__(256) void im2col_k(const float* __restrict__ x, u16* __restrict__ xp) {
  const int i = blockIdx.x * 256 + threadIdx.x;
  const int l = i & 511; const int m = i >> 9;
  const int b = m >> 9, n = m & 511;
  const int h = n >> 6, w = (n >> 3) & 7, d = n & 7;
  const int pi = l >> 6, pj = (l >> 3) & 7, pk = l & 7;
  xp[i] = f2bf(x[(long)b * 262144 + (long)(h * 8 + pi) * 4096 + (w * 8 + pj) * 64 + (d * 8 + pk)]);
}

__global__ __launch_bounds__(256) void castw_k(const float* __restrict__ in, u16* __restrict__ out, int n) {
  for (int i = blockIdx.x * 256 + threadIdx.x; i < n; i += gridDim.x * 256)
    out[i] = f2bf(in[i]);
}

// all 7 [z=4] weight transposes in one grid-stride launch
struct TJ { const float* s[7]; u16* d[7]; };
__global__ __launch_bounds__(256) void transpose_all_k(TJ tj) {
  const long cum[8] = {0, 1769472, 2359296, 2949120, 5308416, 7667712, 10027008, 12386304};
  for (long gi = (long)blockIdx.x * 256 + threadIdx.x; gi < 12386304; gi += (long)gridDim.x * 256) {
    int j = 0;
    #pragma unroll
    for (int t = 1; t < 7; t++) if (gi >= cum[t]) j = t;
    long li = gi - cum[j];
    const int Kj = (j >= 5) ? 1536 : 384;
    const int Nj = (j == 0) ? 1152 : ((j == 3 || j == 4) ? 1536 : 384);
    const long kn = (long)Kj * Nj;
    long z = 0, rem = li;
    #pragma unroll
    for (int t = 0; t < 3; t++) if (rem >= kn) { rem -= kn; z++; }
    long n, k;
    if (Kj == 384) { n = rem / 384; k = rem - n * 384; }
    else           { n = rem / 1536; k = rem - n * 1536; }
    tj.d[j][li] = f2bf(tj.s[j][z * kn + k * Nj + n]);
  }
}

// dense per-head qkv weights -> [4][1152][384] bf16 (n = s*384 + h*64 + d, k = c)
__global__ __launch_bounds__(256) void repack_mqkv_k(const float* __restrict__ qw, const float* __restrict__ kw,
                                                     const float* __restrict__ vw, u16* __restrict__ out) {
  const int j = blockIdx.z;
  const float* srcs[3] = {qw + j * 147456, kw + j * 147456, vw + j * 147456};
  for (int idx = blockIdx.x * 256 + threadIdx.x; idx < 442368; idx += gridDim.x * 256) {
    int r = idx / 384, c = idx - r * 384;
    int s = r / 384;
    int hd = r - s * 384; int h = hd >> 6, d = hd & 63;
    out[(long)j * 442368 + idx] = f2bf(srcs[s][(h * 384 + c) * 64 + d]);
  }
}

// deconv weights [C][O][2][2][2] -> [8][O][C] bf16
__global__ __launch_bounds__(256) void repack_dw_k(const float* __restrict__ in, u16* __restrict__ out) {
  for (int idx = blockIdx.x * 256 + threadIdx.x; idx < 1179648; idx += gridDim.x * 256) {
    int ijk = idx / 147456, rem = idx - ijk * 147456;
    int o = rem / 384, c = rem - o * 384;
    out[idx] = f2bf(in[c * 3072 + o * 8 + ijk]);
  }
}

// v-part of qkv -> vT [b*6+h][64][512] bf16
__global__ __launch_bounds__(256) void vT_k(const u16* __restrict__ qkv, u16* __restrict__ vT) {
  for (int idx = blockIdx.x * 256 + threadIdx.x; idx < 786432; idx += gridDim.x * 256) {
    int z = idx >> 15, d = (idx >> 9) & 63, t = idx & 511;
    int b = z / 6, h = z - b * 6;
    vT[idx] = qkv[((long)(b * 512 + t)) * 1152 + 768 + h * 64 + d];
  }
}

// final 1x1 conv over bf16 activations; scatter per kernel pos ijk
__global__ __launch_bounds__(256) void contract_k(const u16* __restrict__ act, const float* __restrict__ ow,
                                                  const float* __restrict__ ob, float* __restrict__ out, int ijk) {
  __shared__ __align__(16) float tile[16][388];
  __shared__ __align__(16) float wsh[15][388];
  const int tid = threadIdx.x;
  for (int idx = tid; idx < 15 * 384; idx += 256) {
    int kp = idx / 384, c = idx - kp * 384;
    wsh[kp][c] = ow[idx];
  }
  const long row0 = (long)blockIdx.x << 4;
  for (int idx = tid; idx < 16 * 384; idx += 256) {
    int r = idx / 384, c = idx - r * 384;
    tile[r][c] = bf2f(act[(row0 + r) * 384 + c]);
  }
  __syncthreads();
  const int r = tid >> 4, kp = tid & 15;
  if (kp < 15) {
    float acc = 0.f;
    #pragma unroll 8
    for (int c = 0; c < 384; c += 4) {
      float4 a = *(const float4*)&tile[r][c];
      float4 w = *(const float4*)&wsh[kp][c];
      acc += a.x * w.x + a.y * w.y + a.z * w.z + a.w * w.w;
    }
    const int gm = (int)row0 + r;
    const int b = gm >> 12, h = (gm >> 8) & 15, w = (gm >> 4) & 15, d = gm & 15;
    const int i = ijk >> 2, j = (ijk >> 1) & 1, k = ijk & 1;
    const long o = ((long)(b * 15 + kp) << 15) + (2 * h + i) * 1024 + (2 * w + j) * 32 + (2 * d + k);
    out[o] = acc + ob[kp];
  }
}

// ---------------------------------------------------------------------------

static MmP mk(const u16* A, const u16* Bt, const float* bias, void* C,
              int K, int lda, int ldb, int ldc) {
  MmP p{};
  p.A = A; p.Bt = Bt; p.bias = bias; p.C = C;
  p.e1 = p.e2 = p.e3 = p.e4 = nullptr;
  p.K = K; p.ZH = 1; p.lda = lda; p.ldb = ldb; p.ldc = ldc;
  p.aSb = p.aSh = p.bSb = p.bSh = p.cSb = p.cSh = 0;
  return p;
}

extern "C" void kernel_launch(void* const* d_in, const int* in_sizes, int n_in,
                              void* d_out, int out_size, void* d_ws, size_t ws_size,
                              hipStream_t stream) {
  (void)in_sizes; (void)n_in; (void)out_size; (void)ws_size;
  const float* x        = (const float*)d_in[0];
  const float* patch_w  = (const float*)d_in[1];
  const float* patch_b  = (const float*)d_in[2];
  const float* pos_emb  = (const float*)d_in[3];
  const float* m_ln1_g  = (const float*)d_in[4];
  const float* m_ln1_b  = (const float*)d_in[5];
  const float* m_qw     = (const float*)d_in[6];
  const float* m_kw     = (const float*)d_in[7];
  const float* m_vw     = (const float*)d_in[8];
  const float* m_proj_w = (const float*)d_in[9];
  const float* m_proj_b = (const float*)d_in[10];
  const float* m_ln2_g  = (const float*)d_in[11];
  const float* m_ln2_b  = (const float*)d_in[12];
  const float* m_w1     = (const float*)d_in[13];
  const float* m_b1     = (const float*)d_in[14];
  const float* m_w2     = (const float*)d_in[15];
  const float* m_b2     = (const float*)d_in[16];
  const float* s_ln1_g  = (const float*)d_in[17];
  const float* s_ln1_b  = (const float*)d_in[18];
  const float* s_qkv_w  = (const float*)d_in[19];
  const float* s_qkv_b  = (const float*)d_in[20];
  const float* s_proj_w = (const float*)d_in[21];
  const float* s_proj_b = (const float*)d_in[22];
  const float* s_ln2_g  = (const float*)d_in[23];
  const float* s_ln2_b  = (const float*)d_in[24];
  const float* s_w1     = (const float*)d_in[25];
  const float* s_b1     = (const float*)d_in[26];
  const float* s_w2     = (const float*)d_in[27];
  const float* s_b2     = (const float*)d_in[28];
  const float* d1_w     = (const float*)d_in[29];
  const float* d1_b     = (const float*)d_in[30];
  const float* bn1_g    = (const float*)d_in[31];
  const float* bn1_b    = (const float*)d_in[32];
  const float* bn1_m    = (const float*)d_in[33];
  const float* bn1_v    = (const float*)d_in[34];
  const float* d2_w     = (const float*)d_in[35];
  const float* d2_b     = (const float*)d_in[36];
  const float* bn2_g    = (const float*)d_in[37];
  const float* bn2_b    = (const float*)d_in[38];
  const float* bn2_m    = (const float*)d_in[39];
  const float* bn2_v    = (const float*)d_in[40];
  const float* out_w    = (const float*)d_in[41];
  const float* out_b    = (const float*)d_in[42];
  float* out = (float*)d_out;

  // ---- workspace arena ----
  char* wsp = (char*)d_ws;
  auto alloc = [&](size_t bytes) { void* p = wsp; wsp += (bytes + 255) & ~(size_t)255; return p; };
  float* tok    = (float*)alloc(786432 * 4);
  u16* wqkv_m   = (u16*)alloc(1769472 * 2);
  u16* wqkv_s   = (u16*)alloc(1769472 * 2);
  u16* wproj_m  = (u16*)alloc(589824 * 2);
  u16* wproj_s  = (u16*)alloc(589824 * 2);
  u16* w1m      = (u16*)alloc(2359296 * 2);
  u16* w1s      = (u16*)alloc(2359296 * 2);
  u16* w2m      = (u16*)alloc(2359296 * 2);
  u16* w2s      = (u16*)alloc(2359296 * 2);
  u16* wpatch   = (u16*)alloc(196608 * 2);
  u16* wd1      = (u16*)alloc(1179648 * 2);
  u16* wd2      = (u16*)alloc(1179648 * 2);
  u16* lnb      = (u16*)alloc(786432 * 2);
  u16* qkvb     = (u16*)alloc(2359296 * 2);   // qkvb..ffnhb contiguous (aliased by out2b)
  u16* attnob   = (u16*)alloc(786432 * 2);
  u16* ffnhb    = (u16*)alloc(3145728 * 2);
  u16* scoresb  = (u16*)alloc(6291456 * 2);   // 24x512x512; aliased by xp / y1b
  u16* vTb      = (u16*)alloc(786432 * 2);    // aliased by tokb (late)
  u16* xpb   = scoresb;
  u16* y1b   = scoresb;
  u16* out2b = qkvb;
  u16* tokb  = vTb;

  // ---- weight repack ----
  castw_k<<<256, 256, 0, stream>>>(patch_w, wpatch, 196608);
  repack_mqkv_k<<<dim3(128, 1, 4), 256, 0, stream>>>(m_qw, m_kw, m_vw, wqkv_m);
  {
    TJ tj;
    tj.s[0] = s_qkv_w;  tj.d[0] = wqkv_s;
    tj.s[1] = m_proj_w; tj.d[1] = wproj_m;
    tj.s[2] = s_proj_w; tj.d[2] = wproj_s;
    tj.s[3] = m_w1;     tj.d[3] = w1m;
    tj.s[4] = s_w1;     tj.d[4] = w1s;
    tj.s[5] = m_w2;     tj.d[5] = w2m;
    tj.s[6] = s_w2;     tj.d[6] = w2s;
    transpose_all_k<<<2048, 256, 0, stream>>>(tj);
  }
  repack_dw_k<<<512, 256, 0, stream>>>(d1_w, wd1);
  repack_dw_k<<<512, 256, 0, stream>>>(d2_w, wd2);

  // ---- patch embedding + pos_emb -> tok (fp32) ----
  im2col_k<<<4096, 256, 0, stream>>>(x, xpb);
  {
    MmP p = mk(xpb, wpatch, patch_b, tok, 512, 512, 512, 384);
    p.e1 = pos_emb;
    mfma_gemm<1, 64><<<dim3(6, 32, 1), 256, 0, stream>>>(p);
  }

  for (int j = 0; j < 4; j++) {
    // ======== dense block ========
    ln_k<<<512, 256, 0, stream>>>(tok, m_ln1_g + j * 384, m_ln1_b + j * 384, lnb);
    {  // QKV (no bias)
      MmP p = mk(lnb, wqkv_m + (long)j * 442368, nullptr, qkvb, 384, 384, 384, 1152);
      mfma_gemm<0, 128><<<dim3(18, 16, 1), 256, 0, stream>>>(p);
    }
    vT_k<<<512, 256, 0, stream>>>(qkvb, vTb);
    attnsm_k<<<dim3(4, 24, 1), 512, 0, stream>>>(qkvb, scoresb);
    {  // attno = P V per (b,h): M=512 N=64 K=512
      MmP p = mk(scoresb, vTb, nullptr, attnob, 512, 512, 512, 384);
      p.ZH = 6; p.aSb = 1572864; p.aSh = 262144; p.bSb = 196608; p.bSh = 32768;
      p.cSb = 196608; p.cSh = 64;
      mfma_gemm<0, 64><<<dim3(1, 8, 24), 256, 0, stream>>>(p);
    }
    {  // proj + residual -> tok fp32
      MmP p = mk(attnob, wproj_m + (long)j * 147456, m_proj_b + j * 384, tok, 384, 384, 384, 384);
      mfma_gemm<2, 64><<<dim3(6, 32, 1), 256, 0, stream>>>(p);
    }
    ln_k<<<512, 256, 0, stream>>>(tok, m_ln2_g + j * 384, m_ln2_b + j * 384, lnb);
    {  // FFN1 relu
      MmP p = mk(lnb, w1m + (long)j * 589824, m_b1 + j * 1536, ffnhb, 384, 384, 384, 1536);
      mfma_gemm<3, 128><<<dim3(24, 16, 1), 256, 0, stream>>>(p);
    }
    {  // FFN2 + residual
      MmP p = mk(ffnhb, w2m + (long)j * 589824, m_b2 + j * 384, tok, 1536, 1536, 1536, 384);
      mfma_gemm<2, 64><<<dim3(6, 32, 1), 256, 0, stream>>>(p);
    }

    // ======== shifted-window block ========
    ln_k<<<512, 256, 0, stream>>>(tok, s_ln1_g + j * 384, s_ln1_b + j * 384, lnb);
    {
      MmP p = mk(lnb, wqkv_s + (long)j * 442368, s_qkv_b + j * 1152, qkvb, 384, 384, 384, 1152);
      mfma_gemm<0, 128><<<dim3(18, 16, 1), 256, 0, stream>>>(p);
    }
    swin_k<<<1536, 64, 0, stream>>>(qkvb, attnob);
    {
      MmP p = mk(attnob, wproj_s + (long)j * 147456, s_proj_b + j * 384, tok, 384, 384, 384, 384);
      mfma_gemm<2, 64><<<dim3(6, 32, 1), 256, 0, stream>>>(p);
    }
    ln_k<<<512, 256, 0, stream>>>(tok, s_ln2_g + j * 384, s_ln2_b + j * 384, lnb);
    {
      MmP p = mk(lnb, w1s + (long)j * 589824, s_b1 + j * 1536, ffnhb, 384, 384, 384, 1536);
      mfma_gemm<3, 128><<<dim3(24, 16, 1), 256, 0, stream>>>(p);
    }
    {
      MmP p = mk(ffnhb, w2s + (long)j * 589824, s_b2 + j * 384, tok, 1536, 1536, 1536, 384);
      mfma_gemm<2, 64><<<dim3(6, 32, 1), 256, 0, stream>>>(p);
    }
  }

  // ---- decoder ----
  castw_k<<<768, 256, 0, stream>>>(tok, tokb, 786432);
  {  // deconv1 all 8 positions + bn1-relu -> y1b token-major
    MmP p = mk(tokb, wd1, d1_b, y1b, 384, 384, 384, 384);
    p.ZH = 8; p.bSh = 147456;
    p.e1 = bn1_g; p.e2 = bn1_b; p.e3 = bn1_m; p.e4 = bn1_v;
    mfma_gemm<5, 128><<<dim3(6, 16, 8), 256, 0, stream>>>(p);
  }
  for (int ijk = 0; ijk < 8; ijk++) {
    {  // deconv2 position ijk + bn2-relu -> out2b
      MmP p = mk(y1b, wd2 + (long)ijk * 147456, d2_b, out2b, 384, 384, 384, 384);
      p.e1 = bn2_g; p.e2 = bn2_b; p.e3 = bn2_m; p.e4 = bn2_v;
      mfma_gemm<6, 128><<<dim3(6, 128, 1), 256, 0, stream>>>(p);
    }
    contract_k<<<1024, 256, 0, stream>>>(out2b, out_w, out_b, out, ijk);
  }
}

// Round 7
// 1065.557 us; speedup vs baseline: 3.4504x; 1.0681x over previous
//
#include <hip/hip_runtime.h>
#include <hip/hip_bf16.h>

// ---------------------------------------------------------------------------
// TokenPoseWithShiftedWindow — bf16 MFMA, round 6 (resubmit: infra timeout).
// GEMM: 2-phase double-buffered LDS pipeline, BM in {128,64}, BN=64, BK=64,
// 4 waves, mfma_f32_16x16x32_bf16, global_load_lds(16B), XOR-source-swizzle.
// Fused scores+softmax. All weight repacks LDS-tiled (coalesced both sides).
// ---------------------------------------------------------------------------

typedef unsigned short u16;
typedef __bf16 bf16x8 __attribute__((ext_vector_type(8)));
typedef float f32x4 __attribute__((ext_vector_type(4)));

__device__ __forceinline__ u16 f2bf(float f) {
  unsigned u = __builtin_bit_cast(unsigned, f);
  return (u16)((u + 0x7FFFu + ((u >> 16) & 1u)) >> 16);
}
__device__ __forceinline__ float bf2f(u16 b) {
  unsigned u = ((unsigned)b) << 16;
  return __builtin_bit_cast(float, u);
}

#define GLOAD_LDS16(g, l)                                                      \
  __builtin_amdgcn_global_load_lds(                                            \
      (const __attribute__((address_space(1))) unsigned int*)(const void*)(g), \
      (__attribute__((address_space(3))) unsigned int*)(void*)(l), 16, 0, 0)

struct MmP {
  const u16* A;   // bf16 [M][K], row stride lda
  const u16* Bt;  // bf16 [N][K], row stride ldb (B transposed)
  const float* bias;
  void* C;
  void* aux;      // MODE 7: vT output
  const float* e1; const float* e2; const float* e3; const float* e4;
  int K, ZH, lda, ldb, ldc;
  long aSb, aSh, bSb, bSh, cSb, cSh;
};

// MODE: 0 = bf16 store (+bias)            (qkv swin, attn-out)
//       1 = f32 +bias +pos_emb            (patch embed -> tok)
//       2 = f32 residual += (+bias)       (proj, ffn2 -> tok)
//       3 = bf16 relu(+bias)              (ffn1 -> ffnh)
//       5 = bf16 bn-relu deconv1 scatter  (-> y1 token-major)
//       6 = bf16 bn-relu store            (deconv2 -> out2)
//       7 = bf16 store + vT scatter       (qkv dense)
template<int MODE, int BM>
__global__ __launch_bounds__(256) void mfma_gemm(MmP p) {
  const int z = blockIdx.z;
  const int zb = z / p.ZH, zh = z - zb * p.ZH;
  const u16* A  = p.A  + zb * p.aSb + zh * p.aSh;
  const u16* Bt = p.Bt + zb * p.bSb + zh * p.bSh;
  const int m0 = blockIdx.y * BM, n0 = blockIdx.x * 64;

  __shared__ u16 As[2][BM * 64];
  __shared__ u16 Bs[2][64 * 64];

  const int tid = threadIdx.x;
  const int wid = tid >> 6, lane = tid & 63;
  constexpr int MI = BM / 32;
  const int wm = (wid >> 1) * (BM / 2), wn = (wid & 1) * 32;
  const int lr = lane & 15, lg = lane >> 4;
  constexpr int ACH = BM / 32;

  f32x4 acc[MI][2];
  #pragma unroll
  for (int i = 0; i < MI; i++)
    #pragma unroll
    for (int j = 0; j < 2; j++) acc[i][j] = (f32x4){0.f, 0.f, 0.f, 0.f};

  auto stage = [&](int buf, int kt) {
    #pragma unroll
    for (int i = 0; i < ACH; i++) {
      int c = i * 256 + tid;
      int row = c >> 3, cc = c & 7;
      int gk = ((cc ^ (row & 7)) << 3) + (kt << 6);
      GLOAD_LDS16(A + (long)(m0 + row) * p.lda + gk, As[buf] + c * 8);
    }
    #pragma unroll
    for (int i = 0; i < 2; i++) {
      int c = i * 256 + tid;
      int row = c >> 3, cc = c & 7;
      int gk = ((cc ^ (row & 7)) << 3) + (kt << 6);
      GLOAD_LDS16(Bt + (long)(n0 + row) * p.ldb + gk, Bs[buf] + c * 8);
    }
  };

  const int nKT = p.K >> 6;
  stage(0, 0);
  asm volatile("s_waitcnt vmcnt(0)");
  __syncthreads();

  int cur = 0;
  for (int kt = 0; kt < nKT; ++kt) {
    const bool more = (kt + 1 < nKT);
    if (more) stage(cur ^ 1, kt + 1);

    bf16x8 af[MI][2], bfr[2][2];
    #pragma unroll
    for (int i = 0; i < MI; i++)
      #pragma unroll
      for (int ks = 0; ks < 2; ks++) {
        int row = wm + i * 16 + lr;
        int j = ks * 4 + lg;
        af[i][ks] = *(const bf16x8*)(As[cur] + (row * 8 + (j ^ (row & 7))) * 8);
      }
    #pragma unroll
    for (int jn = 0; jn < 2; jn++)
      #pragma unroll
      for (int ks = 0; ks < 2; ks++) {
        int row = wn + jn * 16 + lr;
        int j = ks * 4 + lg;
        bfr[jn][ks] = *(const bf16x8*)(Bs[cur] + (row * 8 + (j ^ (row & 7))) * 8);
      }
    #pragma unroll
    for (int i = 0; i < MI; i++)
      #pragma unroll
      for (int jn = 0; jn < 2; jn++)
        #pragma unroll
        for (int ks = 0; ks < 2; ks++)
          acc[i][jn] = __builtin_amdgcn_mfma_f32_16x16x32_bf16(
              af[i][ks], bfr[jn][ks], acc[i][jn], 0, 0, 0);

    if (more) {
      asm volatile("s_waitcnt vmcnt(0)");
      __syncthreads();
      cur ^= 1;
    }
  }

  // epilogue; C/D layout: col = lane&15, row = (lane>>4)*4 + r
  const long coff = zb * p.cSb + zh * p.cSh;
  #pragma unroll
  for (int i = 0; i < MI; i++) {
    const int rowb = m0 + wm + i * 16 + lg * 4;
    #pragma unroll
    for (int jn = 0; jn < 2; jn++) {
      const int col = n0 + wn + jn * 16 + lr;
      const float bv = p.bias ? p.bias[col] : 0.f;
      #pragma unroll
      for (int r = 0; r < 4; r++) {
        const int row = rowb + r;
        const float v = acc[i][jn][r];
        if constexpr (MODE == 0) {
          ((u16*)p.C)[coff + (long)row * p.ldc + col] = f2bf(v + bv);
        } else if constexpr (MODE == 1) {
          ((float*)p.C)[coff + (long)row * p.ldc + col] =
              v + bv + p.e1[(long)(row & 511) * 384 + col];
        } else if constexpr (MODE == 2) {
          ((float*)p.C)[coff + (long)row * p.ldc + col] += v + bv;
        } else if constexpr (MODE == 3) {
          ((u16*)p.C)[coff + (long)row * p.ldc + col] = f2bf(fmaxf(v + bv, 0.f));
        } else if constexpr (MODE == 5) {
          float raw = v + bv;
          float val = fmaxf((raw - p.e3[col]) * rsqrtf(p.e4[col] + 1e-5f) * p.e1[col] + p.e2[col], 0.f);
          int b = row >> 9, hwd = row & 511;
          int h = hwd >> 6, w = (hwd >> 3) & 7, d = hwd & 7;
          int i_ = zh >> 2, j_ = (zh >> 1) & 1, k_ = zh & 1;
          long tokn = (long)b * 4096 + (2 * h + i_) * 256 + (2 * w + j_) * 16 + (2 * d + k_);
          ((u16*)p.C)[tokn * 384 + col] = f2bf(val);
        } else if constexpr (MODE == 6) {
          float raw = v + bv;
          float val = fmaxf((raw - p.e3[col]) * rsqrtf(p.e4[col] + 1e-5f) * p.e1[col] + p.e2[col], 0.f);
          ((u16*)p.C)[(long)row * p.ldc + col] = f2bf(val);
        } else if constexpr (MODE == 7) {
          u16 bv16 = f2bf(v);
          ((u16*)p.C)[coff + (long)row * p.ldc + col] = bv16;
          if (col >= 768) {  // scatter V into vT [b*6+h][64][512]
            int bb = row >> 9, tt = row & 511;
            int hh = (col - 768) >> 6, dd = col & 63;
            ((u16*)p.aux)[(((long)bb * 6 + hh) << 15) + (dd << 9) + tt] = bv16;
          }
        }
      }
    }
  }
}

// Fused scores+softmax: P = softmax(Q K^T / 8) per (b,h). One block per
// (q-tile of 128, bh); 512 threads; K resident in swizzled LDS.
__global__ __launch_bounds__(512) void attnsm_k(const u16* __restrict__ qkv, u16* __restrict__ P) {
  const int bh = blockIdx.y;
  const int b = bh / 6, h = bh - b * 6;
  const int qt = blockIdx.x;
  const int tid = threadIdx.x, wid = tid >> 6, lane = tid & 63;
  const int lr = lane & 15, lg = lane >> 4;
  __shared__ u16 Ks[512 * 64];
  const u16* qbase = qkv + ((long)b * 512) * 1152 + h * 64;

  #pragma unroll
  for (int i = 0; i < 8; i++) {
    int c = i * 512 + tid;
    int t = c >> 3, cc = c & 7;
    int gk = (cc ^ (t & 7)) << 3;
    GLOAD_LDS16(qbase + (long)t * 1152 + 384 + gk, Ks + c * 8);
  }
  const int qrow = qt * 128 + wid * 16 + lr;
  bf16x8 qf[2];
  #pragma unroll
  for (int ks = 0; ks < 2; ks++)
    qf[ks] = *(const bf16x8*)(qbase + (long)qrow * 1152 + (ks * 4 + lg) * 8);
  asm volatile("s_waitcnt vmcnt(0)");
  __syncthreads();

  f32x4 s[32];
  #pragma unroll
  for (int nt = 0; nt < 32; nt++) {
    s[nt] = (f32x4){0.f, 0.f, 0.f, 0.f};
    #pragma unroll
    for (int ks = 0; ks < 2; ks++) {
      int row = nt * 16 + lr;
      int j = ks * 4 + lg;
      bf16x8 kf = *(const bf16x8*)(Ks + (row * 8 + (j ^ (row & 7))) * 8);
      s[nt] = __builtin_amdgcn_mfma_f32_16x16x32_bf16(qf[ks], kf, s[nt], 0, 0, 0);
    }
  }
  float mx[4] = {-1e30f, -1e30f, -1e30f, -1e30f};
  #pragma unroll
  for (int nt = 0; nt < 32; nt++)
    #pragma unroll
    for (int r = 0; r < 4; r++) { s[nt][r] *= 0.125f; mx[r] = fmaxf(mx[r], s[nt][r]); }
  #pragma unroll
  for (int o = 8; o >= 1; o >>= 1)
    #pragma unroll
    for (int r = 0; r < 4; r++) mx[r] = fmaxf(mx[r], __shfl_xor(mx[r], o));
  float sum[4] = {0.f, 0.f, 0.f, 0.f};
  #pragma unroll
  for (int nt = 0; nt < 32; nt++)
    #pragma unroll
    for (int r = 0; r < 4; r++) { float e = __expf(s[nt][r] - mx[r]); s[nt][r] = e; sum[r] += e; }
  #pragma unroll
  for (int o = 8; o >= 1; o >>= 1)
    #pragma unroll
    for (int r = 0; r < 4; r++) sum[r] += __shfl_xor(sum[r], o);
  float inv[4];
  #pragma unroll
  for (int r = 0; r < 4; r++) inv[r] = 1.f / sum[r];

  u16* Pb = P + (long)bh * 262144;
  const int prow0 = qt * 128 + wid * 16 + lg * 4;
  #pragma unroll
  for (int nt = 0; nt < 32; nt++)
    #pragma unroll
    for (int r = 0; r < 4; r++)
      Pb[(long)(prow0 + r) * 512 + nt * 16 + lr] = f2bf(s[nt][r] * inv[r]);
}

// ---------------- aux kernels ----------------

__global__ __launch_bounds__(256) void ln_k(const float* __restrict__ x, const float* __restrict__ g,
                                            const float* __restrict__ b, u16* __restrict__ y) {
  const int row = (blockIdx.x << 2) + (threadIdx.x >> 6);
  const int lane = threadIdx.x & 63;
  const float* xr = x + (long)row * 384;
  float v[6]; float s = 0.f;
  #pragma unroll
  for (int i = 0; i < 6; i++) { v[i] = xr[lane + (i << 6)]; s += v[i]; }
  #pragma unroll
  for (int o = 32; o >= 1; o >>= 1) s += __shfl_xor(s, o);
  const float mean = s * (1.f / 384.f);
  float q = 0.f;
  #pragma unroll
  for (int i = 0; i < 6; i++) { float dd = v[i] - mean; q += dd * dd; }
  #pragma unroll
  for (int o = 32; o >= 1; o >>= 1) q += __shfl_xor(q, o);
  const float rstd = rsqrtf(q * (1.f / 384.f) + 1e-5f);
  u16* yr = y + (long)row * 384;
  #pragma unroll
  for (int i = 0; i < 6; i++) {
    int c = lane + (i << 6);
    yr[c] = f2bf((v[i] - mean) * rstd * g[c] + b[c]);
  }
}

__global__ __launch_bounds__(64) void swin_k(const u16* __restrict__ qkv, u16* __restrict__ attno) {
  const int blk = blockIdx.x;
  const int h = blk % 6; const int bw = blk / 6;
  const int b = bw >> 6, win = bw & 63;
  const int wh = win >> 4, ww = (win >> 2) & 3, wd = win & 3;
  const int lane = threadIdx.x;
  __shared__ float qs[8][68], ks[8][68], vs[8][68], attw[8][8];
  __shared__ int ntok[8];
  if (lane < 8) {
    int i = lane >> 2, j = (lane >> 1) & 1, k = lane & 1;
    int oh = (2 * wh + i + 1) & 7, ow = (2 * ww + j + 1) & 7, od = (2 * wd + k + 1) & 7;
    ntok[lane] = oh * 64 + ow * 8 + od;
  }
  __syncthreads();
  #pragma unroll
  for (int t = 0; t < 8; t++) {
    long base = ((long)b * 512 + ntok[t]) * 1152 + h * 64 + lane;
    qs[t][lane] = bf2f(qkv[base]);
    ks[t][lane] = bf2f(qkv[base + 384]);
    vs[t][lane] = bf2f(qkv[base + 768]);
  }
  __syncthreads();
  const int tq = lane >> 3, tm = lane & 7;
  float sc = 0.f;
  #pragma unroll 16
  for (int d = 0; d < 64; d++) sc += qs[tq][d] * ks[tm][d];
  sc *= 0.125f;
  float mx = sc;
  mx = fmaxf(mx, __shfl_xor(mx, 4));
  mx = fmaxf(mx, __shfl_xor(mx, 2));
  mx = fmaxf(mx, __shfl_xor(mx, 1));
  float e = __expf(sc - mx);
  float sm = e;
  sm += __shfl_xor(sm, 4); sm += __shfl_xor(sm, 2); sm += __shfl_xor(sm, 1);
  attw[tq][tm] = e / sm;
  __syncthreads();
  #pragma unroll
  for (int t = 0; t < 8; t++) {
    float o = 0.f;
    #pragma unroll
    for (int m = 0; m < 8; m++) o += attw[t][m] * vs[m][lane];
    attno[((long)b * 512 + ntok[t]) * 384 + h * 64 + lane] = f2bf(o);
  }
}

__global__ __launch_bounds__(256) void im2col_k(const float* __restrict__ x, u16* __restrict__ xp) {
  const int i = blockIdx.x * 256 + threadIdx.x;
  const int l = i & 511; const int m = i >> 9;
  const int b = m >> 9, n = m & 511;
  const int h = n >> 6, w = (n >> 3) & 7, d = n & 7;
  const int pi = l >> 6, pj = (l >> 3) & 7, pk = l & 7;
  xp[i] = f2bf(x[(long)b * 262144 + (long)(h * 8 + pi) * 4096 + (w * 8 + pj) * 64 + (d * 8 + pk)]);
}

__global__ __launch_bounds__(256) void castw_k(const float* __restrict__ in, u16* __restrict__ out, int n) {
  for (int i = blockIdx.x * 256 + threadIdx.x; i < n; i += gridDim.x * 256)
    out[i] = f2bf(in[i]);
}

// LDS-tiled transpose+cast for the 7 [z=4][K][N] weights -> [z][N][K] bf16.
struct TJ { const float* s[7]; u16* d[7]; };
__global__ __launch_bounds__(256) void transpose_tiled_k(TJ tj) {
  __shared__ u16 tile[64][65];
  const int cumt[8] = {0, 432, 576, 720, 1296, 1872, 2448, 3024};
  const int bi = blockIdx.x;
  int j = 0;
  #pragma unroll
  for (int t = 1; t < 7; t++) if (bi >= cumt[t]) j = t;
  const int li = bi - cumt[j];
  const int Kj = (j >= 5) ? 1536 : 384;
  const int Nj = (j == 0) ? 1152 : ((j == 3 || j == 4) ? 1536 : 384);
  const int tn_cnt = Nj >> 6;
  const int per_z = (Kj >> 6) * tn_cnt;
  const int z = li / per_z;
  int rem = li - z * per_z;
  const int tk = rem / tn_cnt, tn = rem - tk * tn_cnt;
  const float* src = tj.s[j] + (long)z * Kj * Nj;
  u16* dst = tj.d[j] + (long)z * Kj * Nj;
  const int k0 = tk << 6, n0 = tn << 6;
  const int rl = threadIdx.x >> 6, c = threadIdx.x & 63;
  #pragma unroll
  for (int i = 0; i < 16; i++) {
    int r = i * 4 + rl;
    tile[r][c] = f2bf(src[(long)(k0 + r) * Nj + n0 + c]);
  }
  __syncthreads();
  #pragma unroll
  for (int i = 0; i < 16; i++) {
    int n = i * 4 + rl;
    dst[(long)(n0 + n) * Kj + k0 + c] = tile[c][n];
  }
}

// dense per-head qkv weights -> [4][1152][384] bf16, LDS-tiled.
// block = (layer j, s, head h, c-tile tk); 432 blocks.
__global__ __launch_bounds__(256) void repack_mqkv_k2(const float* __restrict__ qw, const float* __restrict__ kw,
                                                      const float* __restrict__ vw, u16* __restrict__ out) {
  __shared__ u16 tile[64][65];
  const int bi = blockIdx.x;
  const int j = bi / 108;
  int rem = bi - j * 108;
  const int s = rem / 36; rem -= s * 36;
  const int h = rem / 6, tk = rem - h * 6;
  const float* src = (s == 0 ? qw : s == 1 ? kw : vw) + (long)j * 147456;
  const int rl = threadIdx.x >> 6, cc = threadIdx.x & 63;
  #pragma unroll
  for (int i = 0; i < 16; i++) {
    int cl = tk * 64 + i * 4 + rl;  // source row (C dim)
    tile[i * 4 + rl][cc] = f2bf(src[(long)(h * 384 + cl) * 64 + cc]);  // cc = d
  }
  __syncthreads();
  u16* ob = out + (long)j * 442368 + (long)(s * 384 + h * 64) * 384 + tk * 64;
  #pragma unroll
  for (int i = 0; i < 16; i++) {
    int d = i * 4 + rl;
    ob[(long)d * 384 + cc] = tile[cc][d];
  }
}

// deconv weights [C=384][O=384][2][2][2] -> [8][O][C] bf16, LDS-tiled.
// block = (c-tile of 32, o-tile of 64); 72 blocks.
__global__ __launch_bounds__(256) void repack_dw_k2(const float* __restrict__ in, u16* __restrict__ out) {
  __shared__ u16 ds[32][514];
  const int bo = blockIdx.x % 6, bc = blockIdx.x / 6;
  const int c0 = bc * 32, o0 = bo * 64;
  #pragma unroll 4
  for (int it = 0; it < 64; it++) {
    int fl = it * 256 + threadIdx.x;
    int cr = fl >> 9, mm = fl & 511;  // mm = o_local*8 + ijk
    ds[cr][mm] = f2bf(in[(long)(c0 + cr) * 3072 + o0 * 8 + mm]);
  }
  __syncthreads();
  #pragma unroll 4
  for (int it = 0; it < 64; it++) {
    int fl = it * 256 + threadIdx.x;
    int ijk = fl >> 11, rem = fl & 2047;
    int oo = rem >> 5, cr = rem & 31;
    out[(long)ijk * 147456 + (long)(o0 + oo) * 384 + c0 + cr] = ds[cr][oo * 8 + ijk];
  }
}

// final 1x1 conv over bf16 activations; scatter per kernel pos ijk
__global__ __launch_bounds__(256) void contract_k(const u16* __restrict__ act, const float* __restrict__ ow,
                                                  const float* __restrict__ ob, float* __restrict__ out, int ijk) {
  __shared__ __align__(16) float tile[16][388];
  __shared__ __align__(16) float wsh[15][388];
  const int tid = threadIdx.x;
  for (int idx = tid; idx < 15 * 384; idx += 256) {
    int kp = idx / 384, c = idx - kp * 384;
    wsh[kp][c] = ow[idx];
  }
  const long row0 = (long)blockIdx.x << 4;
  for (int idx = tid; idx < 16 * 384; idx += 256) {
    int r = idx / 384, c = idx - r * 384;
    tile[r][c] = bf2f(act[(row0 + r) * 384 + c]);
  }
  __syncthreads();
  const int r = tid >> 4, kp = tid & 15;
  if (kp < 15) {
    float acc = 0.f;
    #pragma unroll 8
    for (int c = 0; c < 384; c += 4) {
      float4 a = *(const float4*)&tile[r][c];
      float4 w = *(const float4*)&wsh[kp][c];
      acc += a.x * w.x + a.y * w.y + a.z * w.z + a.w * w.w;
    }
    const int gm = (int)row0 + r;
    const int b = gm >> 12, h = (gm >> 8) & 15, w = (gm >> 4) & 15, d = gm & 15;
    const int i = ijk >> 2, j = (ijk >> 1) & 1, k = ijk & 1;
    const long o = ((long)(b * 15 + kp) << 15) + (2 * h + i) * 1024 + (2 * w + j) * 32 + (2 * d + k);
    out[o] = acc + ob[kp];
  }
}

// ---------------------------------------------------------------------------

static MmP mk(const u16* A, const u16* Bt, const float* bias, void* C,
              int K, int lda, int ldb, int ldc) {
  MmP p{};
  p.A = A; p.Bt = Bt; p.bias = bias; p.C = C; p.aux = nullptr;
  p.e1 = p.e2 = p.e3 = p.e4 = nullptr;
  p.K = K; p.ZH = 1; p.lda = lda; p.ldb = ldb; p.ldc = ldc;
  p.aSb = p.aSh = p.bSb = p.bSh = p.cSb = p.cSh = 0;
  return p;
}

extern "C" void kernel_launch(void* const* d_in, const int* in_sizes, int n_in,
                              void* d_out, int out_size, void* d_ws, size_t ws_size,
                              hipStream_t stream) {
  (void)in_sizes; (void)n_in; (void)out_size; (void)ws_size;
  const float* x        = (const float*)d_in[0];
  const float* patch_w  = (const float*)d_in[1];
  const float* patch_b  = (const float*)d_in[2];
  const float* pos_emb  = (const float*)d_in[3];
  const float* m_ln1_g  = (const float*)d_in[4];
  const float* m_ln1_b  = (const float*)d_in[5];
  const float* m_qw     = (const float*)d_in[6];
  const float* m_kw     = (const float*)d_in[7];
  const float* m_vw     = (const float*)d_in[8];
  const float* m_proj_w = (const float*)d_in[9];
  const float* m_proj_b = (const float*)d_in[10];
  const float* m_ln2_g  = (const float*)d_in[11];
  const float* m_ln2_b  = (const float*)d_in[12];
  const float* m_w1     = (const float*)d_in[13];
  const float* m_b1     = (const float*)d_in[14];
  const float* m_w2     = (const float*)d_in[15];
  const float* m_b2     = (const float*)d_in[16];
  const float* s_ln1_g  = (const float*)d_in[17];
  const float* s_ln1_b  = (const float*)d_in[18];
  const float* s_qkv_w  = (const float*)d_in[19];
  const float* s_qkv_b  = (const float*)d_in[20];
  const float* s_proj_w = (const float*)d_in[21];
  const float* s_proj_b = (const float*)d_in[22];
  const float* s_ln2_g  = (const float*)d_in[23];
  const float* s_ln2_b  = (const float*)d_in[24];
  const float* s_w1     = (const float*)d_in[25];
  const float* s_b1     = (const float*)d_in[26];
  const float* s_w2     = (const float*)d_in[27];
  const float* s_b2     = (const float*)d_in[28];
  const float* d1_w     = (const float*)d_in[29];
  const float* d1_b     = (const float*)d_in[30];
  const float* bn1_g    = (const float*)d_in[31];
  const float* bn1_b    = (const float*)d_in[32];
  const float* bn1_m    = (const float*)d_in[33];
  const float* bn1_v    = (const float*)d_in[34];
  const float* d2_w     = (const float*)d_in[35];
  const float* d2_b     = (const float*)d_in[36];
  const float* bn2_g    = (const float*)d_in[37];
  const float* bn2_b    = (const float*)d_in[38];
  const float* bn2_m    = (const float*)d_in[39];
  const float* bn2_v    = (const float*)d_in[40];
  const float* out_w    = (const float*)d_in[41];
  const float* out_b    = (const float*)d_in[42];
  float* out = (float*)d_out;

  // ---- workspace arena ----
  char* wsp = (char*)d_ws;
  auto alloc = [&](size_t bytes) { void* p = wsp; wsp += (bytes + 255) & ~(size_t)255; return p; };
  float* tok    = (float*)alloc(786432 * 4);
  u16* wqkv_m   = (u16*)alloc(1769472 * 2);
  u16* wqkv_s   = (u16*)alloc(1769472 * 2);
  u16* wproj_m  = (u16*)alloc(589824 * 2);
  u16* wproj_s  = (u16*)alloc(589824 * 2);
  u16* w1m      = (u16*)alloc(2359296 * 2);
  u16* w1s      = (u16*)alloc(2359296 * 2);
  u16* w2m      = (u16*)alloc(2359296 * 2);
  u16* w2s      = (u16*)alloc(2359296 * 2);
  u16* wpatch   = (u16*)alloc(196608 * 2);
  u16* wd1      = (u16*)alloc(1179648 * 2);
  u16* wd2      = (u16*)alloc(1179648 * 2);
  u16* lnb      = (u16*)alloc(786432 * 2);
  u16* qkvb     = (u16*)alloc(2359296 * 2);   // qkvb..ffnhb contiguous (aliased by out2b)
  u16* attnob   = (u16*)alloc(786432 * 2);
  u16* ffnhb    = (u16*)alloc(3145728 * 2);
  u16* scoresb  = (u16*)alloc(6291456 * 2);   // 24x512x512; aliased by xp / y1b
  u16* vTb      = (u16*)alloc(786432 * 2);    // aliased by tokb (late)
  u16* xpb   = scoresb;
  u16* y1b   = scoresb;
  u16* out2b = qkvb;
  u16* tokb  = vTb;

  // ---- weight repack (all LDS-tiled, coalesced) ----
  castw_k<<<256, 256, 0, stream>>>(patch_w, wpatch, 196608);
  repack_mqkv_k2<<<432, 256, 0, stream>>>(m_qw, m_kw, m_vw, wqkv_m);
  {
    TJ tj;
    tj.s[0] = s_qkv_w;  tj.d[0] = wqkv_s;
    tj.s[1] = m_proj_w; tj.d[1] = wproj_m;
    tj.s[2] = s_proj_w; tj.d[2] = wproj_s;
    tj.s[3] = m_w1;     tj.d[3] = w1m;
    tj.s[4] = s_w1;     tj.d[4] = w1s;
    tj.s[5] = m_w2;     tj.d[5] = w2m;
    tj.s[6] = s_w2;     tj.d[6] = w2s;
    transpose_tiled_k<<<3024, 256, 0, stream>>>(tj);
  }
  repack_dw_k2<<<72, 256, 0, stream>>>(d1_w, wd1);
  repack_dw_k2<<<72, 256, 0, stream>>>(d2_w, wd2);

  // ---- patch embedding + pos_emb -> tok (fp32) ----
  im2col_k<<<4096, 256, 0, stream>>>(x, xpb);
  {
    MmP p = mk(xpb, wpatch, patch_b, tok, 512, 512, 512, 384);
    p.e1 = pos_emb;
    mfma_gemm<1, 64><<<dim3(6, 32, 1), 256, 0, stream>>>(p);
  }

  for (int j = 0; j < 4; j++) {
    // ======== dense block ========
    ln_k<<<512, 256, 0, stream>>>(tok, m_ln1_g + j * 384, m_ln1_b + j * 384, lnb);
    {  // QKV (no bias) + fused vT scatter
      MmP p = mk(lnb, wqkv_m + (long)j * 442368, nullptr, qkvb, 384, 384, 384, 1152);
      p.aux = vTb;
      mfma_gemm<7, 128><<<dim3(18, 16, 1), 256, 0, stream>>>(p);
    }
    attnsm_k<<<dim3(4, 24, 1), 512, 0, stream>>>(qkvb, scoresb);
    {  // attno = P V per (b,h): M=512 N=64 K=512
      MmP p = mk(scoresb, vTb, nullptr, attnob, 512, 512, 512, 384);
      p.ZH = 6; p.aSb = 1572864; p.aSh = 262144; p.bSb = 196608; p.bSh = 32768;
      p.cSb = 196608; p.cSh = 64;
      mfma_gemm<0, 64><<<dim3(1, 8, 24), 256, 0, stream>>>(p);
    }
    {  // proj + residual -> tok fp32
      MmP p = mk(attnob, wproj_m + (long)j * 147456, m_proj_b + j * 384, tok, 384, 384, 384, 384);
      mfma_gemm<2, 64><<<dim3(6, 32, 1), 256, 0, stream>>>(p);
    }
    ln_k<<<512, 256, 0, stream>>>(tok, m_ln2_g + j * 384, m_ln2_b + j * 384, lnb);
    {  // FFN1 relu
      MmP p = mk(lnb, w1m + (long)j * 589824, m_b1 + j * 1536, ffnhb, 384, 384, 384, 1536);
      mfma_gemm<3, 128><<<dim3(24, 16, 1), 256, 0, stream>>>(p);
    }
    {  // FFN2 + residual
      MmP p = mk(ffnhb, w2m + (long)j * 589824, m_b2 + j * 384, tok, 1536, 1536, 1536, 384);
      mfma_gemm<2, 64><<<dim3(6, 32, 1), 256, 0, stream>>>(p);
    }

    // ======== shifted-window block ========
    ln_k<<<512, 256, 0, stream>>>(tok, s_ln1_g + j * 384, s_ln1_b + j * 384, lnb);
    {
      MmP p = mk(lnb, wqkv_s + (long)j * 442368, s_qkv_b + j * 1152, qkvb, 384, 384, 384, 1152);
      mfma_gemm<0, 128><<<dim3(18, 16, 1), 256, 0, stream>>>(p);
    }
    swin_k<<<1536, 64, 0, stream>>>(qkvb, attnob);
    {
      MmP p = mk(attnob, wproj_s + (long)j * 147456, s_proj_b + j * 384, tok, 384, 384, 384, 384);
      mfma_gemm<2, 64><<<dim3(6, 32, 1), 256, 0, stream>>>(p);
    }
    ln_k<<<512, 256, 0, stream>>>(tok, s_ln2_g + j * 384, s_ln2_b + j * 384, lnb);
    {
      MmP p = mk(lnb, w1s + (long)j * 589824, s_b1 + j * 1536, ffnhb, 384, 384, 384, 1536);
      mfma_gemm<3, 128><<<dim3(24, 16, 1), 256, 0, stream>>>(p);
    }
    {
      MmP p = mk(ffnhb, w2s + (long)j * 589824, s_b2 + j * 384, tok, 1536, 1536, 1536, 384);
      mfma_gemm<2, 64><<<dim3(6, 32, 1), 256, 0, stream>>>(p);
    }
  }

  // ---- decoder ----
  castw_k<<<768, 256, 0, stream>>>(tok, tokb, 786432);
  {  // deconv1 all 8 positions + bn1-relu -> y1b token-major
    MmP p = mk(tokb, wd1, d1_b, y1b, 384, 384, 384, 384);
    p.ZH = 8; p.bSh = 147456;
    p.e1 = bn1_g; p.e2 = bn1_b; p.e3 = bn1_m; p.e4 = bn1_v;
    mfma_gemm<5, 128><<<dim3(6, 16, 8), 256, 0, stream>>>(p);
  }
  for (int ijk = 0; ijk < 8; ijk++) {
    {  // deconv2 position ijk + bn2-relu -> out2b
      MmP p = mk(y1b, wd2 + (long)ijk * 147456, d2_b, out2b, 384, 384, 384, 384);
      p.e1 = bn2_g; p.e2 = bn2_b; p.e3 = bn2_m; p.e4 = bn2_v;
      mfma_gemm<6, 128><<<dim3(6, 128, 1), 256, 0, stream>>>(p);
    }
    contract_k<<<1024, 256, 0, stream>>>(out2b, out_w, out_b, out, ijk);
  }
}

// Round 8
// 960.060 us; speedup vs baseline: 3.8296x; 1.1099x over previous
//
#include <hip/hip_runtime.h>
#include <hip/hip_bf16.h>

// ---------------------------------------------------------------------------
// TokenPoseWithShiftedWindow — bf16 MFMA, round 8.
// New: fused deconv2+bn+relu+contract kernel (dc2_k) replaces 16 launches;
// attnsm split to 192 blocks; repack_dw merged. GEMM core unchanged.
// ---------------------------------------------------------------------------

typedef unsigned short u16;
typedef __bf16 bf16x8 __attribute__((ext_vector_type(8)));
typedef unsigned short u16x8 __attribute__((ext_vector_type(8)));
typedef float f32x4 __attribute__((ext_vector_type(4)));

__device__ __forceinline__ u16 f2bf(float f) {
  unsigned u = __builtin_bit_cast(unsigned, f);
  return (u16)((u + 0x7FFFu + ((u >> 16) & 1u)) >> 16);
}
__device__ __forceinline__ float bf2f(u16 b) {
  unsigned u = ((unsigned)b) << 16;
  return __builtin_bit_cast(float, u);
}

#define GLOAD_LDS16(g, l)                                                      \
  __builtin_amdgcn_global_load_lds(                                            \
      (const __attribute__((address_space(1))) unsigned int*)(const void*)(g), \
      (__attribute__((address_space(3))) unsigned int*)(void*)(l), 16, 0, 0)

struct MmP {
  const u16* A;   // bf16 [M][K], row stride lda
  const u16* Bt;  // bf16 [N][K], row stride ldb (B transposed)
  const float* bias;
  void* C;
  void* aux;      // MODE 7: vT output
  const float* e1; const float* e2; const float* e3; const float* e4;
  int K, ZH, lda, ldb, ldc;
  long aSb, aSh, bSb, bSh, cSb, cSh;
};

// MODE: 0 = bf16 store (+bias)            (qkv swin, attn-out)
//       1 = f32 +bias +pos_emb            (patch embed -> tok)
//       2 = f32 residual += (+bias)       (proj, ffn2 -> tok)
//       3 = bf16 relu(+bias)              (ffn1 -> ffnh)
//       5 = bf16 bn-relu deconv1 scatter  (-> y1 token-major)
//       7 = bf16 store + vT scatter       (qkv dense)
template<int MODE, int BM>
__global__ __launch_bounds__(256) void mfma_gemm(MmP p) {
  const int z = blockIdx.z;
  const int zb = z / p.ZH, zh = z - zb * p.ZH;
  const u16* A  = p.A  + zb * p.aSb + zh * p.aSh;
  const u16* Bt = p.Bt + zb * p.bSb + zh * p.bSh;
  const int m0 = blockIdx.y * BM, n0 = blockIdx.x * 64;

  __shared__ u16 As[2][BM * 64];
  __shared__ u16 Bs[2][64 * 64];

  const int tid = threadIdx.x;
  const int wid = tid >> 6, lane = tid & 63;
  constexpr int MI = BM / 32;
  const int wm = (wid >> 1) * (BM / 2), wn = (wid & 1) * 32;
  const int lr = lane & 15, lg = lane >> 4;
  constexpr int ACH = BM / 32;

  f32x4 acc[MI][2];
  #pragma unroll
  for (int i = 0; i < MI; i++)
    #pragma unroll
    for (int j = 0; j < 2; j++) acc[i][j] = (f32x4){0.f, 0.f, 0.f, 0.f};

  auto stage = [&](int buf, int kt) {
    #pragma unroll
    for (int i = 0; i < ACH; i++) {
      int c = i * 256 + tid;
      int row = c >> 3, cc = c & 7;
      int gk = ((cc ^ (row & 7)) << 3) + (kt << 6);
      GLOAD_LDS16(A + (long)(m0 + row) * p.lda + gk, As[buf] + c * 8);
    }
    #pragma unroll
    for (int i = 0; i < 2; i++) {
      int c = i * 256 + tid;
      int row = c >> 3, cc = c & 7;
      int gk = ((cc ^ (row & 7)) << 3) + (kt << 6);
      GLOAD_LDS16(Bt + (long)(n0 + row) * p.ldb + gk, Bs[buf] + c * 8);
    }
  };

  const int nKT = p.K >> 6;
  stage(0, 0);
  asm volatile("s_waitcnt vmcnt(0)");
  __syncthreads();

  int cur = 0;
  for (int kt = 0; kt < nKT; ++kt) {
    const bool more = (kt + 1 < nKT);
    if (more) stage(cur ^ 1, kt + 1);

    bf16x8 af[MI][2], bfr[2][2];
    #pragma unroll
    for (int i = 0; i < MI; i++)
      #pragma unroll
      for (int ks = 0; ks < 2; ks++) {
        int row = wm + i * 16 + lr;
        int j = ks * 4 + lg;
        af[i][ks] = *(const bf16x8*)(As[cur] + (row * 8 + (j ^ (row & 7))) * 8);
      }
    #pragma unroll
    for (int jn = 0; jn < 2; jn++)
      #pragma unroll
      for (int ks = 0; ks < 2; ks++) {
        int row = wn + jn * 16 + lr;
        int j = ks * 4 + lg;
        bfr[jn][ks] = *(const bf16x8*)(Bs[cur] + (row * 8 + (j ^ (row & 7))) * 8);
      }
    #pragma unroll
    for (int i = 0; i < MI; i++)
      #pragma unroll
      for (int jn = 0; jn < 2; jn++)
        #pragma unroll
        for (int ks = 0; ks < 2; ks++)
          acc[i][jn] = __builtin_amdgcn_mfma_f32_16x16x32_bf16(
              af[i][ks], bfr[jn][ks], acc[i][jn], 0, 0, 0);

    if (more) {
      asm volatile("s_waitcnt vmcnt(0)");
      __syncthreads();
      cur ^= 1;
    }
  }

  // epilogue; C/D layout: col = lane&15, row = (lane>>4)*4 + r
  const long coff = zb * p.cSb + zh * p.cSh;
  #pragma unroll
  for (int i = 0; i < MI; i++) {
    const int rowb = m0 + wm + i * 16 + lg * 4;
    #pragma unroll
    for (int jn = 0; jn < 2; jn++) {
      const int col = n0 + wn + jn * 16 + lr;
      const float bv = p.bias ? p.bias[col] : 0.f;
      #pragma unroll
      for (int r = 0; r < 4; r++) {
        const int row = rowb + r;
        const float v = acc[i][jn][r];
        if constexpr (MODE == 0) {
          ((u16*)p.C)[coff + (long)row * p.ldc + col] = f2bf(v + bv);
        } else if constexpr (MODE == 1) {
          ((float*)p.C)[coff + (long)row * p.ldc + col] =
              v + bv + p.e1[(long)(row & 511) * 384 + col];
        } else if constexpr (MODE == 2) {
          ((float*)p.C)[coff + (long)row * p.ldc + col] += v + bv;
        } else if constexpr (MODE == 3) {
          ((u16*)p.C)[coff + (long)row * p.ldc + col] = f2bf(fmaxf(v + bv, 0.f));
        } else if constexpr (MODE == 5) {
          float raw = v + bv;
          float val = fmaxf((raw - p.e3[col]) * rsqrtf(p.e4[col] + 1e-5f) * p.e1[col] + p.e2[col], 0.f);
          int b = row >> 9, hwd = row & 511;
          int h = hwd >> 6, w = (hwd >> 3) & 7, d = hwd & 7;
          int i_ = zh >> 2, j_ = (zh >> 1) & 1, k_ = zh & 1;
          long tokn = (long)b * 4096 + (2 * h + i_) * 256 + (2 * w + j_) * 16 + (2 * d + k_);
          ((u16*)p.C)[tokn * 384 + col] = f2bf(val);
        } else if constexpr (MODE == 7) {
          u16 bv16 = f2bf(v);
          ((u16*)p.C)[coff + (long)row * p.ldc + col] = bv16;
          if (col >= 768) {  // scatter V into vT [b*6+h][64][512]
            int bb = row >> 9, tt = row & 511;
            int hh = (col - 768) >> 6, dd = col & 63;
            ((u16*)p.aux)[(((long)bb * 6 + hh) << 15) + (dd << 9) + tt] = bv16;
          }
        }
      }
    }
  }
}

// Fused deconv2 + bn2 + relu + out_w contraction + scatter, one launch.
// grid (256, 8): x = 64-row m-tile of y1 [16384][384], y = kernel position ijk.
__global__ __launch_bounds__(512) void dc2_k(const u16* __restrict__ y1, const u16* __restrict__ wd2,
                                             const float* __restrict__ d2b,
                                             const float* __restrict__ g, const float* __restrict__ bta,
                                             const float* __restrict__ mu, const float* __restrict__ var,
                                             const float* __restrict__ ow, const float* __restrict__ ob,
                                             float* __restrict__ out) {
  __shared__ char smem[114688];           // 112 KB
  u16* As = (u16*)smem;                    // [2][64*64]   (16 KB)
  u16* Bs = (u16*)(smem + 16384);          // [2][384*64]  (96 KB)
  u16* H2 = (u16*)(smem + 16384);          // [64][392]    (overlaps Bs, post-loop)
  float* ows = (float*)(smem + 16384 + 50176);  // [15][388]

  const int ijk = blockIdx.y;
  const int m0 = blockIdx.x * 64;
  const u16* Bt = wd2 + (long)ijk * 147456;
  const int tid = threadIdx.x;
  const int wid = tid >> 6, lane = tid & 63;
  const int wr = wid >> 2, wc = wid & 3;   // 2 x 4 wave grid; wave tile 32x96
  const int lr = lane & 15, lg = lane >> 4;

  f32x4 acc[2][6];
  #pragma unroll
  for (int i = 0; i < 2; i++)
    #pragma unroll
    for (int j = 0; j < 6; j++) acc[i][j] = (f32x4){0.f, 0.f, 0.f, 0.f};

  auto stage = [&](int buf, int kt) {
    {
      int c = tid;
      int row = c >> 3, cc = c & 7;
      int gk = ((cc ^ (row & 7)) << 3) + (kt << 6);
      GLOAD_LDS16(y1 + (long)(m0 + row) * 384 + gk, As + buf * 4096 + c * 8);
    }
    #pragma unroll
    for (int i = 0; i < 6; i++) {
      int c = i * 512 + tid;
      int row = c >> 3, cc = c & 7;
      int gk = ((cc ^ (row & 7)) << 3) + (kt << 6);
      GLOAD_LDS16(Bt + (long)row * 384 + gk, Bs + buf * 24576 + c * 8);
    }
  };
  stage(0, 0);
  asm volatile("s_waitcnt vmcnt(0)");
  __syncthreads();
  int cur = 0;
  for (int kt = 0; kt < 6; ++kt) {
    const bool more = (kt < 5);
    if (more) stage(cur ^ 1, kt + 1);
    bf16x8 af[2][2], bfr[6][2];
    #pragma unroll
    for (int i = 0; i < 2; i++)
      #pragma unroll
      for (int ks = 0; ks < 2; ks++) {
        int row = wr * 32 + i * 16 + lr;
        int j = ks * 4 + lg;
        af[i][ks] = *(const bf16x8*)(As + cur * 4096 + (row * 8 + (j ^ (row & 7))) * 8);
      }
    #pragma unroll
    for (int jn = 0; jn < 6; jn++)
      #pragma unroll
      for (int ks = 0; ks < 2; ks++) {
        int row = wc * 96 + jn * 16 + lr;
        int j = ks * 4 + lg;
        bfr[jn][ks] = *(const bf16x8*)(Bs + cur * 24576 + (row * 8 + (j ^ (row & 7))) * 8);
      }
    #pragma unroll
    for (int i = 0; i < 2; i++)
      #pragma unroll
      for (int jn = 0; jn < 6; jn++)
        #pragma unroll
        for (int ks = 0; ks < 2; ks++)
          acc[i][jn] = __builtin_amdgcn_mfma_f32_16x16x32_bf16(
              af[i][ks], bfr[jn][ks], acc[i][jn], 0, 0, 0);
    if (more) {
      asm volatile("s_waitcnt vmcnt(0)");
      __syncthreads();
      cur ^= 1;
    }
  }
  __syncthreads();  // all waves done reading Bs before it becomes H2

  // bn2 + relu -> H2 (bf16, LDS)
  #pragma unroll
  for (int i = 0; i < 2; i++)
    #pragma unroll
    for (int jn = 0; jn < 6; jn++) {
      const int col = wc * 96 + jn * 16 + lr;
      const float scale = rsqrtf(var[col] + 1e-5f) * g[col];
      const float bias2 = bta[col] - mu[col] * scale;
      const float db = d2b[col];
      #pragma unroll
      for (int r = 0; r < 4; r++) {
        int row = wr * 32 + i * 16 + lg * 4 + r;
        float val = fmaxf((acc[i][jn][r] + db) * scale + bias2, 0.f);
        H2[row * 392 + col] = f2bf(val);
      }
    }
  for (int idx = tid; idx < 15 * 384; idx += 512) {
    int kp = idx / 384, c = idx - kp * 384;
    ows[kp * 388 + c] = ow[idx];
  }
  __syncthreads();

  // contract: 64 rows x 15 keypoints, dot over 384
  const int kp = tid & 15, rbase = tid >> 4;  // rbase 0..31
  if (kp < 15) {
    const int i_ = ijk >> 2, j_ = (ijk >> 1) & 1, k_ = ijk & 1;
    #pragma unroll
    for (int pass = 0; pass < 2; pass++) {
      const int r = rbase + pass * 32;
      float a = 0.f;
      #pragma unroll 4
      for (int c = 0; c < 384; c += 8) {
        u16x8 hv = *(const u16x8*)&H2[r * 392 + c];
        const float* wp = &ows[kp * 388 + c];
        #pragma unroll
        for (int u = 0; u < 8; u++) a += bf2f(hv[u]) * wp[u];
      }
      const int gm = m0 + r;
      const int b = gm >> 12, h = (gm >> 8) & 15, w = (gm >> 4) & 15, d = gm & 15;
      const long o = ((long)(b * 15 + kp) << 15) + (2 * h + i_) * 1024 + (2 * w + j_) * 32 + (2 * d + k_);
      out[o] = a + ob[kp];
    }
  }
}

// Fused scores+softmax: P = softmax(Q K^T / 8) per (b,h). One block per
// (q-tile of 64, bh); 256 threads (4 waves x 16 q-rows); K in swizzled LDS.
__global__ __launch_bounds__(256) void attnsm_k(const u16* __restrict__ qkv, u16* __restrict__ P) {
  const int bh = blockIdx.y;
  const int b = bh / 6, h = bh - b * 6;
  const int qt = blockIdx.x;
  const int tid = threadIdx.x, wid = tid >> 6, lane = tid & 63;
  const int lr = lane & 15, lg = lane >> 4;
  __shared__ u16 Ks[512 * 64];
  const u16* qbase = qkv + ((long)b * 512) * 1152 + h * 64;

  #pragma unroll
  for (int i = 0; i < 16; i++) {
    int c = i * 256 + tid;
    int t = c >> 3, cc = c & 7;
    int gk = (cc ^ (t & 7)) << 3;
    GLOAD_LDS16(qbase + (long)t * 1152 + 384 + gk, Ks + c * 8);
  }
  const int qrow = qt * 64 + wid * 16 + lr;
  bf16x8 qf[2];
  #pragma unroll
  for (int ks = 0; ks < 2; ks++)
    qf[ks] = *(const bf16x8*)(qbase + (long)qrow * 1152 + (ks * 4 + lg) * 8);
  asm volatile("s_waitcnt vmcnt(0)");
  __syncthreads();

  f32x4 s[32];
  #pragma unroll
  for (int nt = 0; nt < 32; nt++) {
    s[nt] = (f32x4){0.f, 0.f, 0.f, 0.f};
    #pragma unroll
    for (int ks = 0; ks < 2; ks++) {
      int row = nt * 16 + lr;
      int j = ks * 4 + lg;
      bf16x8 kf = *(const bf16x8*)(Ks + (row * 8 + (j ^ (row & 7))) * 8);
      s[nt] = __builtin_amdgcn_mfma_f32_16x16x32_bf16(qf[ks], kf, s[nt], 0, 0, 0);
    }
  }
  float mx[4] = {-1e30f, -1e30f, -1e30f, -1e30f};
  #pragma unroll
  for (int nt = 0; nt < 32; nt++)
    #pragma unroll
    for (int r = 0; r < 4; r++) { s[nt][r] *= 0.125f; mx[r] = fmaxf(mx[r], s[nt][r]); }
  #pragma unroll
  for (int o = 8; o >= 1; o >>= 1)
    #pragma unroll
    for (int r = 0; r < 4; r++) mx[r] = fmaxf(mx[r], __shfl_xor(mx[r], o));
  float sum[4] = {0.f, 0.f, 0.f, 0.f};
  #pragma unroll
  for (int nt = 0; nt < 32; nt++)
    #pragma unroll
    for (int r = 0; r < 4; r++) { float e = __expf(s[nt][r] - mx[r]); s[nt][r] = e; sum[r] += e; }
  #pragma unroll
  for (int o = 8; o >= 1; o >>= 1)
    #pragma unroll
    for (int r = 0; r < 4; r++) sum[r] += __shfl_xor(sum[r], o);
  float inv[4];
  #pragma unroll
  for (int r = 0; r < 4; r++) inv[r] = 1.f / sum[r];

  u16* Pb = P + (long)bh * 262144;
  const int prow0 = qt * 64 + wid * 16 + lg * 4;
  #pragma unroll
  for (int nt = 0; nt < 32; nt++)
    #pragma unroll
    for (int r = 0; r < 4; r++)
      Pb[(long)(prow0 + r) * 512 + nt * 16 + lr] = f2bf(s[nt][r] * inv[r]);
}

// ---------------- aux kernels ----------------

__global__ __launch_bounds__(256) void ln_k(const float* __restrict__ x, const float* __restrict__ g,
                                            const float* __restrict__ b, u16* __restrict__ y) {
  const int row = (blockIdx.x << 2) + (threadIdx.x >> 6);
  const int lane = threadIdx.x & 63;
  const float* xr = x + (long)row * 384;
  float v[6]; float s = 0.f;
  #pragma unroll
  for (int i = 0; i < 6; i++) { v[i] = xr[lane + (i << 6)]; s += v[i]; }
  #pragma unroll
  for (int o = 32; o >= 1; o >>= 1) s += __shfl_xor(s, o);
  const float mean = s * (1.f / 384.f);
  float q = 0.f;
  #pragma unroll
  for (int i = 0; i < 6; i++) { float dd = v[i] - mean; q += dd * dd; }
  #pragma unroll
  for (int o = 32; o >= 1; o >>= 1) q += __shfl_xor(q, o);
  const float rstd = rsqrtf(q * (1.f / 384.f) + 1e-5f);
  u16* yr = y + (long)row * 384;
  #pragma unroll
  for (int i = 0; i < 6; i++) {
    int c = lane + (i << 6);
    yr[c] = f2bf((v[i] - mean) * rstd * g[c] + b[c]);
  }
}

__global__ __launch_bounds__(64) void swin_k(const u16* __restrict__ qkv, u16* __restrict__ attno) {
  const int blk = blockIdx.x;
  const int h = blk % 6; const int bw = blk / 6;
  const int b = bw >> 6, win = bw & 63;
  const int wh = win >> 4, ww = (win >> 2) & 3, wd = win & 3;
  const int lane = threadIdx.x;
  __shared__ float qs[8][68], ks[8][68], vs[8][68], attw[8][8];
  __shared__ int ntok[8];
  if (lane < 8) {
    int i = lane >> 2, j = (lane >> 1) & 1, k = lane & 1;
    int oh = (2 * wh + i + 1) & 7, ow = (2 * ww + j + 1) & 7, od = (2 * wd + k + 1) & 7;
    ntok[lane] = oh * 64 + ow * 8 + od;
  }
  __syncthreads();
  #pragma unroll
  for (int t = 0; t < 8; t++) {
    long base = ((long)b * 512 + ntok[t]) * 1152 + h * 64 + lane;
    qs[t][lane] = bf2f(qkv[base]);
    ks[t][lane] = bf2f(qkv[base + 384]);
    vs[t][lane] = bf2f(qkv[base + 768]);
  }
  __syncthreads();
  const int tq = lane >> 3, tm = lane & 7;
  float sc = 0.f;
  #pragma unroll 16
  for (int d = 0; d < 64; d++) sc += qs[tq][d] * ks[tm][d];
  sc *= 0.125f;
  float mx = sc;
  mx = fmaxf(mx, __shfl_xor(mx, 4));
  mx = fmaxf(mx, __shfl_xor(mx, 2));
  mx = fmaxf(mx, __shfl_xor(mx, 1));
  float e = __expf(sc - mx);
  float sm = e;
  sm += __shfl_xor(sm, 4); sm += __shfl_xor(sm, 2); sm += __shfl_xor(sm, 1);
  attw[tq][tm] = e / sm;
  __syncthreads();
  #pragma unroll
  for (int t = 0; t < 8; t++) {
    float o = 0.f;
    #pragma unroll
    for (int m = 0; m < 8; m++) o += attw[t][m] * vs[m][lane];
    attno[((long)b * 512 + ntok[t]) * 384 + h * 64 + lane] = f2bf(o);
  }
}

__global__ __launch_bounds__(256) void im2col_k(const float* __restrict__ x, u16* __restrict__ xp) {
  const int i = blockIdx.x * 256 + threadIdx.x;
  const int l = i & 511; const int m = i >> 9;
  const int b = m >> 9, n = m & 511;
  const int h = n >> 6, w = (n >> 3) & 7, d = n & 7;
  const int pi = l >> 6, pj = (l >> 3) & 7, pk = l & 7;
  xp[i] = f2bf(x[(long)b * 262144 + (long)(h * 8 + pi) * 4096 + (w * 8 + pj) * 64 + (d * 8 + pk)]);
}

__global__ __launch_bounds__(256) void castw_k(const float* __restrict__ in, u16* __restrict__ out, int n) {
  for (int i = blockIdx.x * 256 + threadIdx.x; i < n; i += gridDim.x * 256)
    out[i] = f2bf(in[i]);
}

// LDS-tiled transpose+cast for the 7 [z=4][K][N] weights -> [z][N][K] bf16.
struct TJ { const float* s[7]; u16* d[7]; };
__global__ __launch_bounds__(256) void transpose_tiled_k(TJ tj) {
  __shared__ u16 tile[64][65];
  const int cumt[8] = {0, 432, 576, 720, 1296, 1872, 2448, 3024};
  const int bi = blockIdx.x;
  int j = 0;
  #pragma unroll
  for (int t = 1; t < 7; t++) if (bi >= cumt[t]) j = t;
  const int li = bi - cumt[j];
  const int Kj = (j >= 5) ? 1536 : 384;
  const int Nj = (j == 0) ? 1152 : ((j == 3 || j == 4) ? 1536 : 384);
  const int tn_cnt = Nj >> 6;
  const int per_z = (Kj >> 6) * tn_cnt;
  const int z = li / per_z;
  int rem = li - z * per_z;
  const int tk = rem / tn_cnt, tn = rem - tk * tn_cnt;
  const float* src = tj.s[j] + (long)z * Kj * Nj;
  u16* dst = tj.d[j] + (long)z * Kj * Nj;
  const int k0 = tk << 6, n0 = tn << 6;
  const int rl = threadIdx.x >> 6, c = threadIdx.x & 63;
  #pragma unroll
  for (int i = 0; i < 16; i++) {
    int r = i * 4 + rl;
    tile[r][c] = f2bf(src[(long)(k0 + r) * Nj + n0 + c]);
  }
  __syncthreads();
  #pragma unroll
  for (int i = 0; i < 16; i++) {
    int n = i * 4 + rl;
    dst[(long)(n0 + n) * Kj + k0 + c] = tile[c][n];
  }
}

// dense per-head qkv weights -> [4][1152][384] bf16, LDS-tiled. 432 blocks.
__global__ __launch_bounds__(256) void repack_mqkv_k2(const float* __restrict__ qw, const float* __restrict__ kw,
                                                      const float* __restrict__ vw, u16* __restrict__ out) {
  __shared__ u16 tile[64][65];
  const int bi = blockIdx.x;
  const int j = bi / 108;
  int rem = bi - j * 108;
  const int s = rem / 36; rem -= s * 36;
  const int h = rem / 6, tk = rem - h * 6;
  const float* src = (s == 0 ? qw : s == 1 ? kw : vw) + (long)j * 147456;
  const int rl = threadIdx.x >> 6, cc = threadIdx.x & 63;
  #pragma unroll
  for (int i = 0; i < 16; i++) {
    int cl = tk * 64 + i * 4 + rl;
    tile[i * 4 + rl][cc] = f2bf(src[(long)(h * 384 + cl) * 64 + cc]);
  }
  __syncthreads();
  u16* ob = out + (long)j * 442368 + (long)(s * 384 + h * 64) * 384 + tk * 64;
  #pragma unroll
  for (int i = 0; i < 16; i++) {
    int d = i * 4 + rl;
    ob[(long)d * 384 + cc] = tile[cc][d];
  }
}

// both deconv weights [C][O][2][2][2] -> [8][O][C] bf16, one launch (144 blocks).
__global__ __launch_bounds__(256) void repack_dw2_k(const float* __restrict__ in1, u16* __restrict__ out1,
                                                    const float* __restrict__ in2, u16* __restrict__ out2) {
  __shared__ u16 ds[32][514];
  const int sel = blockIdx.x >= 72;
  const float* in = sel ? in2 : in1;
  u16* out = sel ? out2 : out1;
  const int bx = sel ? blockIdx.x - 72 : blockIdx.x;
  const int bo = bx % 6, bc = bx / 6;
  const int c0 = bc * 32, o0 = bo * 64;
  #pragma unroll 4
  for (int it = 0; it < 64; it++) {
    int fl = it * 256 + threadIdx.x;
    int cr = fl >> 9, mm = fl & 511;
    ds[cr][mm] = f2bf(in[(long)(c0 + cr) * 3072 + o0 * 8 + mm]);
  }
  __syncthreads();
  #pragma unroll 4
  for (int it = 0; it < 64; it++) {
    int fl = it * 256 + threadIdx.x;
    int ijk = fl >> 11, rem = fl & 2047;
    int oo = rem >> 5, cr = rem & 31;
    out[(long)ijk * 147456 + (long)(o0 + oo) * 384 + c0 + cr] = ds[cr][oo * 8 + ijk];
  }
}

// ---------------------------------------------------------------------------

static MmP mk(const u16* A, const u16* Bt, const float* bias, void* C,
              int K, int lda, int ldb, int ldc) {
  MmP p{};
  p.A = A; p.Bt = Bt; p.bias = bias; p.C = C; p.aux = nullptr;
  p.e1 = p.e2 = p.e3 = p.e4 = nullptr;
  p.K = K; p.ZH = 1; p.lda = lda; p.ldb = ldb; p.ldc = ldc;
  p.aSb = p.aSh = p.bSb = p.bSh = p.cSb = p.cSh = 0;
  return p;
}

extern "C" void kernel_launch(void* const* d_in, const int* in_sizes, int n_in,
                              void* d_out, int out_size, void* d_ws, size_t ws_size,
                              hipStream_t stream) {
  (void)in_sizes; (void)n_in; (void)out_size; (void)ws_size;
  const float* x        = (const float*)d_in[0];
  const float* patch_w  = (const float*)d_in[1];
  const float* patch_b  = (const float*)d_in[2];
  const float* pos_emb  = (const float*)d_in[3];
  const float* m_ln1_g  = (const float*)d_in[4];
  const float* m_ln1_b  = (const float*)d_in[5];
  const float* m_qw     = (const float*)d_in[6];
  const float* m_kw     = (const float*)d_in[7];
  const float* m_vw     = (const float*)d_in[8];
  const float* m_proj_w = (const float*)d_in[9];
  const float* m_proj_b = (const float*)d_in[10];
  const float* m_ln2_g  = (const float*)d_in[11];
  const float* m_ln2_b  = (const float*)d_in[12];
  const float* m_w1     = (const float*)d_in[13];
  const float* m_b1     = (const float*)d_in[14];
  const float* m_w2     = (const float*)d_in[15];
  const float* m_b2     = (const float*)d_in[16];
  const float* s_ln1_g  = (const float*)d_in[17];
  const float* s_ln1_b  = (const float*)d_in[18];
  const float* s_qkv_w  = (const float*)d_in[19];
  const float* s_qkv_b  = (const float*)d_in[20];
  const float* s_proj_w = (const float*)d_in[21];
  const float* s_proj_b = (const float*)d_in[22];
  const float* s_ln2_g  = (const float*)d_in[23];
  const float* s_ln2_b  = (const float*)d_in[24];
  const float* s_w1     = (const float*)d_in[25];
  const float* s_b1     = (const float*)d_in[26];
  const float* s_w2     = (const float*)d_in[27];
  const float* s_b2     = (const float*)d_in[28];
  const float* d1_w     = (const float*)d_in[29];
  const float* d1_b     = (const float*)d_in[30];
  const float* bn1_g    = (const float*)d_in[31];
  const float* bn1_b    = (const float*)d_in[32];
  const float* bn1_m    = (const float*)d_in[33];
  const float* bn1_v    = (const float*)d_in[34];
  const float* d2_w     = (const float*)d_in[35];
  const float* d2_b     = (const float*)d_in[36];
  const float* bn2_g    = (const float*)d_in[37];
  const float* bn2_b    = (const float*)d_in[38];
  const float* bn2_m    = (const float*)d_in[39];
  const float* bn2_v    = (const float*)d_in[40];
  const float* out_w    = (const float*)d_in[41];
  const float* out_b    = (const float*)d_in[42];
  float* out = (float*)d_out;

  // ---- workspace arena ----
  char* wsp = (char*)d_ws;
  auto alloc = [&](size_t bytes) { void* p = wsp; wsp += (bytes + 255) & ~(size_t)255; return p; };
  float* tok    = (float*)alloc(786432 * 4);
  u16* wqkv_m   = (u16*)alloc(1769472 * 2);
  u16* wqkv_s   = (u16*)alloc(1769472 * 2);
  u16* wproj_m  = (u16*)alloc(589824 * 2);
  u16* wproj_s  = (u16*)alloc(589824 * 2);
  u16* w1m      = (u16*)alloc(2359296 * 2);
  u16* w1s      = (u16*)alloc(2359296 * 2);
  u16* w2m      = (u16*)alloc(2359296 * 2);
  u16* w2s      = (u16*)alloc(2359296 * 2);
  u16* wpatch   = (u16*)alloc(196608 * 2);
  u16* wd1      = (u16*)alloc(1179648 * 2);
  u16* wd2      = (u16*)alloc(1179648 * 2);
  u16* lnb      = (u16*)alloc(786432 * 2);
  u16* qkvb     = (u16*)alloc(2359296 * 2);
  u16* attnob   = (u16*)alloc(786432 * 2);
  u16* ffnhb    = (u16*)alloc(3145728 * 2);
  u16* scoresb  = (u16*)alloc(6291456 * 2);   // 24x512x512; aliased by xp / y1b
  u16* vTb      = (u16*)alloc(786432 * 2);    // aliased by tokb (late)
  u16* xpb   = scoresb;
  u16* y1b   = scoresb;
  u16* tokb  = vTb;

  // ---- weight repack (all LDS-tiled, coalesced) ----
  castw_k<<<256, 256, 0, stream>>>(patch_w, wpatch, 196608);
  repack_mqkv_k2<<<432, 256, 0, stream>>>(m_qw, m_kw, m_vw, wqkv_m);
  {
    TJ tj;
    tj.s[0] = s_qkv_w;  tj.d[0] = wqkv_s;
    tj.s[1] = m_proj_w; tj.d[1] = wproj_m;
    tj.s[2] = s_proj_w; tj.d[2] = wproj_s;
    tj.s[3] = m_w1;     tj.d[3] = w1m;
    tj.s[4] = s_w1;     tj.d[4] = w1s;
    tj.s[5] = m_w2;     tj.d[5] = w2m;
    tj.s[6] = s_w2;     tj.d[6] = w2s;
    transpose_tiled_k<<<3024, 256, 0, stream>>>(tj);
  }
  repack_dw2_k<<<144, 256, 0, stream>>>(d1_w, wd1, d2_w, wd2);

  // ---- patch embedding + pos_emb -> tok (fp32) ----
  im2col_k<<<4096, 256, 0, stream>>>(x, xpb);
  {
    MmP p = mk(xpb, wpatch, patch_b, tok, 512, 512, 512, 384);
    p.e1 = pos_emb;
    mfma_gemm<1, 64><<<dim3(6, 32, 1), 256, 0, stream>>>(p);
  }

  for (int j = 0; j < 4; j++) {
    // ======== dense block ========
    ln_k<<<512, 256, 0, stream>>>(tok, m_ln1_g + j * 384, m_ln1_b + j * 384, lnb);
    {  // QKV (no bias) + fused vT scatter
      MmP p = mk(lnb, wqkv_m + (long)j * 442368, nullptr, qkvb, 384, 384, 384, 1152);
      p.aux = vTb;
      mfma_gemm<7, 128><<<dim3(18, 16, 1), 256, 0, stream>>>(p);
    }
    attnsm_k<<<dim3(8, 24, 1), 256, 0, stream>>>(qkvb, scoresb);
    {  // attno = P V per (b,h): M=512 N=64 K=512
      MmP p = mk(scoresb, vTb, nullptr, attnob, 512, 512, 512, 384);
      p.ZH = 6; p.aSb = 1572864; p.aSh = 262144; p.bSb = 196608; p.bSh = 32768;
      p.cSb = 196608; p.cSh = 64;
      mfma_gemm<0, 64><<<dim3(1, 8, 24), 256, 0, stream>>>(p);
    }
    {  // proj + residual -> tok fp32
      MmP p = mk(attnob, wproj_m + (long)j * 147456, m_proj_b + j * 384, tok, 384, 384, 384, 384);
      mfma_gemm<2, 64><<<dim3(6, 32, 1), 256, 0, stream>>>(p);
    }
    ln_k<<<512, 256, 0, stream>>>(tok, m_ln2_g + j * 384, m_ln2_b + j * 384, lnb);
    {  // FFN1 relu
      MmP p = mk(lnb, w1m + (long)j * 589824, m_b1 + j * 1536, ffnhb, 384, 384, 384, 1536);
      mfma_gemm<3, 128><<<dim3(24, 16, 1), 256, 0, stream>>>(p);
    }
    {  // FFN2 + residual
      MmP p = mk(ffnhb, w2m + (long)j * 589824, m_b2 + j * 384, tok, 1536, 1536, 1536, 384);
      mfma_gemm<2, 64><<<dim3(6, 32, 1), 256, 0, stream>>>(p);
    }

    // ======== shifted-window block ========
    ln_k<<<512, 256, 0, stream>>>(tok, s_ln1_g + j * 384, s_ln1_b + j * 384, lnb);
    {
      MmP p = mk(lnb, wqkv_s + (long)j * 442368, s_qkv_b + j * 1152, qkvb, 384, 384, 384, 1152);
      mfma_gemm<0, 128><<<dim3(18, 16, 1), 256, 0, stream>>>(p);
    }
    swin_k<<<1536, 64, 0, stream>>>(qkvb, attnob);
    {
      MmP p = mk(attnob, wproj_s + (long)j * 147456, s_proj_b + j * 384, tok, 384, 384, 384, 384);
      mfma_gemm<2, 64><<<dim3(6, 32, 1), 256, 0, stream>>>(p);
    }
    ln_k<<<512, 256, 0, stream>>>(tok, s_ln2_g + j * 384, s_ln2_b + j * 384, lnb);
    {
      MmP p = mk(lnb, w1s + (long)j * 589824, s_b1 + j * 1536, ffnhb, 384, 384, 384, 1536);
      mfma_gemm<3, 128><<<dim3(24, 16, 1), 256, 0, stream>>>(p);
    }
    {
      MmP p = mk(ffnhb, w2s + (long)j * 589824, s_b2 + j * 384, tok, 1536, 1536, 1536, 384);
      mfma_gemm<2, 64><<<dim3(6, 32, 1), 256, 0, stream>>>(p);
    }
  }

  // ---- decoder ----
  castw_k<<<768, 256, 0, stream>>>(tok, tokb, 786432);
  {  // deconv1 all 8 positions + bn1-relu -> y1b token-major
    MmP p = mk(tokb, wd1, d1_b, y1b, 384, 384, 384, 384);
    p.ZH = 8; p.bSh = 147456;
    p.e1 = bn1_g; p.e2 = bn1_b; p.e3 = bn1_m; p.e4 = bn1_v;
    mfma_gemm<5, 128><<<dim3(6, 16, 8), 256, 0, stream>>>(p);
  }
  // fused deconv2 + bn2 + relu + out_w contraction (replaces 16 launches)
  dc2_k<<<dim3(256, 8, 1), 512, 0, stream>>>(y1b, wd2, d2_b, bn2_g, bn2_b, bn2_m, bn2_v,
                                             out_w, out_b, out);
}

// Round 9
// 878.447 us; speedup vs baseline: 4.1854x; 1.0929x over previous
//
#include <hip/hip_runtime.h>
#include <hip/hip_bf16.h>

// ---------------------------------------------------------------------------
// TokenPoseWithShiftedWindow — bf16 MFMA, round 9.
// dc2_k contraction moved from scalar VALU to MFMA (owT pre-repacked).
// ---------------------------------------------------------------------------

typedef unsigned short u16;
typedef __bf16 bf16x8 __attribute__((ext_vector_type(8)));
typedef unsigned short u16x8 __attribute__((ext_vector_type(8)));
typedef float f32x4 __attribute__((ext_vector_type(4)));

__device__ __forceinline__ u16 f2bf(float f) {
  unsigned u = __builtin_bit_cast(unsigned, f);
  return (u16)((u + 0x7FFFu + ((u >> 16) & 1u)) >> 16);
}
__device__ __forceinline__ float bf2f(u16 b) {
  unsigned u = ((unsigned)b) << 16;
  return __builtin_bit_cast(float, u);
}

#define GLOAD_LDS16(g, l)                                                      \
  __builtin_amdgcn_global_load_lds(                                            \
      (const __attribute__((address_space(1))) unsigned int*)(const void*)(g), \
      (__attribute__((address_space(3))) unsigned int*)(void*)(l), 16, 0, 0)

struct MmP {
  const u16* A;   // bf16 [M][K], row stride lda
  const u16* Bt;  // bf16 [N][K], row stride ldb (B transposed)
  const float* bias;
  void* C;
  void* aux;      // MODE 7: vT output
  const float* e1; const float* e2; const float* e3; const float* e4;
  int K, ZH, lda, ldb, ldc;
  long aSb, aSh, bSb, bSh, cSb, cSh;
};

// MODE: 0 = bf16 store (+bias)            (qkv swin, attn-out)
//       1 = f32 +bias +pos_emb            (patch embed -> tok)
//       2 = f32 residual += (+bias)       (proj, ffn2 -> tok)
//       3 = bf16 relu(+bias)              (ffn1 -> ffnh)
//       5 = bf16 bn-relu deconv1 scatter  (-> y1 token-major)
//       7 = bf16 store + vT scatter       (qkv dense)
template<int MODE, int BM>
__global__ __launch_bounds__(256) void mfma_gemm(MmP p) {
  const int z = blockIdx.z;
  const int zb = z / p.ZH, zh = z - zb * p.ZH;
  const u16* A  = p.A  + zb * p.aSb + zh * p.aSh;
  const u16* Bt = p.Bt + zb * p.bSb + zh * p.bSh;
  const int m0 = blockIdx.y * BM, n0 = blockIdx.x * 64;

  __shared__ u16 As[2][BM * 64];
  __shared__ u16 Bs[2][64 * 64];

  const int tid = threadIdx.x;
  const int wid = tid >> 6, lane = tid & 63;
  constexpr int MI = BM / 32;
  const int wm = (wid >> 1) * (BM / 2), wn = (wid & 1) * 32;
  const int lr = lane & 15, lg = lane >> 4;
  constexpr int ACH = BM / 32;

  f32x4 acc[MI][2];
  #pragma unroll
  for (int i = 0; i < MI; i++)
    #pragma unroll
    for (int j = 0; j < 2; j++) acc[i][j] = (f32x4){0.f, 0.f, 0.f, 0.f};

  auto stage = [&](int buf, int kt) {
    #pragma unroll
    for (int i = 0; i < ACH; i++) {
      int c = i * 256 + tid;
      int row = c >> 3, cc = c & 7;
      int gk = ((cc ^ (row & 7)) << 3) + (kt << 6);
      GLOAD_LDS16(A + (long)(m0 + row) * p.lda + gk, As[buf] + c * 8);
    }
    #pragma unroll
    for (int i = 0; i < 2; i++) {
      int c = i * 256 + tid;
      int row = c >> 3, cc = c & 7;
      int gk = ((cc ^ (row & 7)) << 3) + (kt << 6);
      GLOAD_LDS16(Bt + (long)(n0 + row) * p.ldb + gk, Bs[buf] + c * 8);
    }
  };

  const int nKT = p.K >> 6;
  stage(0, 0);
  asm volatile("s_waitcnt vmcnt(0)");
  __syncthreads();

  int cur = 0;
  for (int kt = 0; kt < nKT; ++kt) {
    const bool more = (kt + 1 < nKT);
    if (more) stage(cur ^ 1, kt + 1);

    bf16x8 af[MI][2], bfr[2][2];
    #pragma unroll
    for (int i = 0; i < MI; i++)
      #pragma unroll
      for (int ks = 0; ks < 2; ks++) {
        int row = wm + i * 16 + lr;
        int j = ks * 4 + lg;
        af[i][ks] = *(const bf16x8*)(As[cur] + (row * 8 + (j ^ (row & 7))) * 8);
      }
    #pragma unroll
    for (int jn = 0; jn < 2; jn++)
      #pragma unroll
      for (int ks = 0; ks < 2; ks++) {
        int row = wn + jn * 16 + lr;
        int j = ks * 4 + lg;
        bfr[jn][ks] = *(const bf16x8*)(Bs[cur] + (row * 8 + (j ^ (row & 7))) * 8);
      }
    #pragma unroll
    for (int i = 0; i < MI; i++)
      #pragma unroll
      for (int jn = 0; jn < 2; jn++)
        #pragma unroll
        for (int ks = 0; ks < 2; ks++)
          acc[i][jn] = __builtin_amdgcn_mfma_f32_16x16x32_bf16(
              af[i][ks], bfr[jn][ks], acc[i][jn], 0, 0, 0);

    if (more) {
      asm volatile("s_waitcnt vmcnt(0)");
      __syncthreads();
      cur ^= 1;
    }
  }

  // epilogue; C/D layout: col = lane&15, row = (lane>>4)*4 + r
  const long coff = zb * p.cSb + zh * p.cSh;
  #pragma unroll
  for (int i = 0; i < MI; i++) {
    const int rowb = m0 + wm + i * 16 + lg * 4;
    #pragma unroll
    for (int jn = 0; jn < 2; jn++) {
      const int col = n0 + wn + jn * 16 + lr;
      const float bv = p.bias ? p.bias[col] : 0.f;
      #pragma unroll
      for (int r = 0; r < 4; r++) {
        const int row = rowb + r;
        const float v = acc[i][jn][r];
        if constexpr (MODE == 0) {
          ((u16*)p.C)[coff + (long)row * p.ldc + col] = f2bf(v + bv);
        } else if constexpr (MODE == 1) {
          ((float*)p.C)[coff + (long)row * p.ldc + col] =
              v + bv + p.e1[(long)(row & 511) * 384 + col];
        } else if constexpr (MODE == 2) {
          ((float*)p.C)[coff + (long)row * p.ldc + col] += v + bv;
        } else if constexpr (MODE == 3) {
          ((u16*)p.C)[coff + (long)row * p.ldc + col] = f2bf(fmaxf(v + bv, 0.f));
        } else if constexpr (MODE == 5) {
          float raw = v + bv;
          float val = fmaxf((raw - p.e3[col]) * rsqrtf(p.e4[col] + 1e-5f) * p.e1[col] + p.e2[col], 0.f);
          int b = row >> 9, hwd = row & 511;
          int h = hwd >> 6, w = (hwd >> 3) & 7, d = hwd & 7;
          int i_ = zh >> 2, j_ = (zh >> 1) & 1, k_ = zh & 1;
          long tokn = (long)b * 4096 + (2 * h + i_) * 256 + (2 * w + j_) * 16 + (2 * d + k_);
          ((u16*)p.C)[tokn * 384 + col] = f2bf(val);
        } else if constexpr (MODE == 7) {
          u16 bv16 = f2bf(v);
          ((u16*)p.C)[coff + (long)row * p.ldc + col] = bv16;
          if (col >= 768) {  // scatter V into vT [b*6+h][64][512]
            int bb = row >> 9, tt = row & 511;
            int hh = (col - 768) >> 6, dd = col & 63;
            ((u16*)p.aux)[(((long)bb * 6 + hh) << 15) + (dd << 9) + tt] = bv16;
          }
        }
      }
    }
  }
}

// Fused deconv2 + bn2 + relu + MFMA out_w contraction + scatter.
// grid (256, 8): x = 64-row m-tile of y1 [16384][384], y = kernel position ijk.
// owT: [16][384] bf16, row kp (kp=15 zero).
__global__ __launch_bounds__(512) void dc2_k(const u16* __restrict__ y1, const u16* __restrict__ wd2,
                                             const float* __restrict__ d2b,
                                             const float* __restrict__ g, const float* __restrict__ bta,
                                             const float* __restrict__ mu, const float* __restrict__ var,
                                             const u16* __restrict__ owT, const float* __restrict__ ob,
                                             float* __restrict__ out) {
  __shared__ char smem[114688];           // 112 KB
  u16* As = (u16*)smem;                    // [2][64*64]   (16 KB)
  u16* Bs = (u16*)(smem + 16384);          // [2][384*64]  (96 KB)
  u16* H2 = (u16*)(smem + 16384);          // [64][392] bf16 (50 KB, overlaps Bs post-loop)

  const int ijk = blockIdx.y;
  const int m0 = blockIdx.x * 64;
  const u16* Bt = wd2 + (long)ijk * 147456;
  const int tid = threadIdx.x;
  const int wid = tid >> 6, lane = tid & 63;
  const int wr = wid >> 2, wc = wid & 3;   // 2 x 4 wave grid; wave tile 32x96
  const int lr = lane & 15, lg = lane >> 4;

  f32x4 acc[2][6];
  #pragma unroll
  for (int i = 0; i < 2; i++)
    #pragma unroll
    for (int j = 0; j < 6; j++) acc[i][j] = (f32x4){0.f, 0.f, 0.f, 0.f};

  auto stage = [&](int buf, int kt) {
    {
      int c = tid;
      int row = c >> 3, cc = c & 7;
      int gk = ((cc ^ (row & 7)) << 3) + (kt << 6);
      GLOAD_LDS16(y1 + (long)(m0 + row) * 384 + gk, As + buf * 4096 + c * 8);
    }
    #pragma unroll
    for (int i = 0; i < 6; i++) {
      int c = i * 512 + tid;
      int row = c >> 3, cc = c & 7;
      int gk = ((cc ^ (row & 7)) << 3) + (kt << 6);
      GLOAD_LDS16(Bt + (long)row * 384 + gk, Bs + buf * 24576 + c * 8);
    }
  };
  stage(0, 0);
  asm volatile("s_waitcnt vmcnt(0)");
  __syncthreads();
  int cur = 0;
  for (int kt = 0; kt < 6; ++kt) {
    const bool more = (kt < 5);
    if (more) stage(cur ^ 1, kt + 1);
    bf16x8 af[2][2], bfr[6][2];
    #pragma unroll
    for (int i = 0; i < 2; i++)
      #pragma unroll
      for (int ks = 0; ks < 2; ks++) {
        int row = wr * 32 + i * 16 + lr;
        int j = ks * 4 + lg;
        af[i][ks] = *(const bf16x8*)(As + cur * 4096 + (row * 8 + (j ^ (row & 7))) * 8);
      }
    #pragma unroll
    for (int jn = 0; jn < 6; jn++)
      #pragma unroll
      for (int ks = 0; ks < 2; ks++) {
        int row = wc * 96 + jn * 16 + lr;
        int j = ks * 4 + lg;
        bfr[jn][ks] = *(const bf16x8*)(Bs + cur * 24576 + (row * 8 + (j ^ (row & 7))) * 8);
      }
    #pragma unroll
    for (int i = 0; i < 2; i++)
      #pragma unroll
      for (int jn = 0; jn < 6; jn++)
        #pragma unroll
        for (int ks = 0; ks < 2; ks++)
          acc[i][jn] = __builtin_amdgcn_mfma_f32_16x16x32_bf16(
              af[i][ks], bfr[jn][ks], acc[i][jn], 0, 0, 0);
    if (more) {
      asm volatile("s_waitcnt vmcnt(0)");
      __syncthreads();
      cur ^= 1;
    }
  }
  __syncthreads();  // all waves done reading Bs before it becomes H2

  // bn2 + relu -> H2 [64][392] bf16 (linear; pad 392 keeps reads ~2-way)
  #pragma unroll
  for (int i = 0; i < 2; i++)
    #pragma unroll
    for (int jn = 0; jn < 6; jn++) {
      const int col = wc * 96 + jn * 16 + lr;
      const float scale = rsqrtf(var[col] + 1e-5f) * g[col];
      const float bias2 = bta[col] - mu[col] * scale;
      const float db = d2b[col];
      #pragma unroll
      for (int r = 0; r < 4; r++) {
        int row = wr * 32 + i * 16 + lg * 4 + r;
        float val = fmaxf((acc[i][jn][r] + db) * scale + bias2, 0.f);
        H2[row * 392 + col] = f2bf(val);
      }
    }
  __syncthreads();

  // MFMA contraction: waves 0-3, wave w does rows [w*16, w*16+16) x owT[16][384]
  if (wid < 4) {
    f32x4 c4 = (f32x4){0.f, 0.f, 0.f, 0.f};
    #pragma unroll
    for (int mf = 0; mf < 12; mf++) {
      bf16x8 af = *(const bf16x8*)(H2 + (wid * 16 + lr) * 392 + mf * 32 + lg * 8);
      bf16x8 bf = *(const bf16x8*)(owT + lr * 384 + mf * 32 + lg * 8);
      c4 = __builtin_amdgcn_mfma_f32_16x16x32_bf16(af, bf, c4, 0, 0, 0);
    }
    // D: col = lane&15 = kp, row = w*16 + lg*4 + r
    if (lr < 15) {
      const int i_ = ijk >> 2, j_ = (ijk >> 1) & 1, k_ = ijk & 1;
      const float bkp = ob[lr];
      #pragma unroll
      for (int r = 0; r < 4; r++) {
        const int gm = m0 + wid * 16 + lg * 4 + r;
        const int b = gm >> 12, h = (gm >> 8) & 15, w = (gm >> 4) & 15, d = gm & 15;
        const long o = ((long)(b * 15 + lr) << 15) + (2 * h + i_) * 1024 + (2 * w + j_) * 32 + (2 * d + k_);
        out[o] = c4[r] + bkp;
      }
    }
  }
}

// Fused scores+softmax: P = softmax(Q K^T / 8) per (b,h). One block per
// (q-tile of 64, bh); 256 threads (4 waves x 16 q-rows); K in swizzled LDS.
__global__ __launch_bounds__(256) void attnsm_k(const u16* __restrict__ qkv, u16* __restrict__ P) {
  const int bh = blockIdx.y;
  const int b = bh / 6, h = bh - b * 6;
  const int qt = blockIdx.x;
  const int tid = threadIdx.x, wid = tid >> 6, lane = tid & 63;
  const int lr = lane & 15, lg = lane >> 4;
  __shared__ u16 Ks[512 * 64];
  const u16* qbase = qkv + ((long)b * 512) * 1152 + h * 64;

  #pragma unroll
  for (int i = 0; i < 16; i++) {
    int c = i * 256 + tid;
    int t = c >> 3, cc = c & 7;
    int gk = (cc ^ (t & 7)) << 3;
    GLOAD_LDS16(qbase + (long)t * 1152 + 384 + gk, Ks + c * 8);
  }
  const int qrow = qt * 64 + wid * 16 + lr;
  bf16x8 qf[2];
  #pragma unroll
  for (int ks = 0; ks < 2; ks++)
    qf[ks] = *(const bf16x8*)(qbase + (long)qrow * 1152 + (ks * 4 + lg) * 8);
  asm volatile("s_waitcnt vmcnt(0)");
  __syncthreads();

  f32x4 s[32];
  #pragma unroll
  for (int nt = 0; nt < 32; nt++) {
    s[nt] = (f32x4){0.f, 0.f, 0.f, 0.f};
    #pragma unroll
    for (int ks = 0; ks < 2; ks++) {
      int row = nt * 16 + lr;
      int j = ks * 4 + lg;
      bf16x8 kf = *(const bf16x8*)(Ks + (row * 8 + (j ^ (row & 7))) * 8);
      s[nt] = __builtin_amdgcn_mfma_f32_16x16x32_bf16(qf[ks], kf, s[nt], 0, 0, 0);
    }
  }
  float mx[4] = {-1e30f, -1e30f, -1e30f, -1e30f};
  #pragma unroll
  for (int nt = 0; nt < 32; nt++)
    #pragma unroll
    for (int r = 0; r < 4; r++) { s[nt][r] *= 0.125f; mx[r] = fmaxf(mx[r], s[nt][r]); }
  #pragma unroll
  for (int o = 8; o >= 1; o >>= 1)
    #pragma unroll
    for (int r = 0; r < 4; r++) mx[r] = fmaxf(mx[r], __shfl_xor(mx[r], o));
  float sum[4] = {0.f, 0.f, 0.f, 0.f};
  #pragma unroll
  for (int nt = 0; nt < 32; nt++)
    #pragma unroll
    for (int r = 0; r < 4; r++) { float e = __expf(s[nt][r] - mx[r]); s[nt][r] = e; sum[r] += e; }
  #pragma unroll
  for (int o = 8; o >= 1; o >>= 1)
    #pragma unroll
    for (int r = 0; r < 4; r++) sum[r] += __shfl_xor(sum[r], o);
  float inv[4];
  #pragma unroll
  for (int r = 0; r < 4; r++) inv[r] = 1.f / sum[r];

  u16* Pb = P + (long)bh * 262144;
  const int prow0 = qt * 64 + wid * 16 + lg * 4;
  #pragma unroll
  for (int nt = 0; nt < 32; nt++)
    #pragma unroll
    for (int r = 0; r < 4; r++)
      Pb[(long)(prow0 + r) * 512 + nt * 16 + lr] = f2bf(s[nt][r] * inv[r]);
}

// ---------------- aux kernels ----------------

__global__ __launch_bounds__(256) void ln_k(const float* __restrict__ x, const float* __restrict__ g,
                                            const float* __restrict__ b, u16* __restrict__ y) {
  const int row = (blockIdx.x << 2) + (threadIdx.x >> 6);
  const int lane = threadIdx.x & 63;
  const float* xr = x + (long)row * 384;
  float v[6]; float s = 0.f;
  #pragma unroll
  for (int i = 0; i < 6; i++) { v[i] = xr[lane + (i << 6)]; s += v[i]; }
  #pragma unroll
  for (int o = 32; o >= 1; o >>= 1) s += __shfl_xor(s, o);
  const float mean = s * (1.f / 384.f);
  float q = 0.f;
  #pragma unroll
  for (int i = 0; i < 6; i++) { float dd = v[i] - mean; q += dd * dd; }
  #pragma unroll
  for (int o = 32; o >= 1; o >>= 1) q += __shfl_xor(q, o);
  const float rstd = rsqrtf(q * (1.f / 384.f) + 1e-5f);
  u16* yr = y + (long)row * 384;
  #pragma unroll
  for (int i = 0; i < 6; i++) {
    int c = lane + (i << 6);
    yr[c] = f2bf((v[i] - mean) * rstd * g[c] + b[c]);
  }
}

__global__ __launch_bounds__(64) void swin_k(const u16* __restrict__ qkv, u16* __restrict__ attno) {
  const int blk = blockIdx.x;
  const int h = blk % 6; const int bw = blk / 6;
  const int b = bw >> 6, win = bw & 63;
  const int wh = win >> 4, ww = (win >> 2) & 3, wd = win & 3;
  const int lane = threadIdx.x;
  __shared__ float qs[8][68], ks[8][68], vs[8][68], attw[8][8];
  __shared__ int ntok[8];
  if (lane < 8) {
    int i = lane >> 2, j = (lane >> 1) & 1, k = lane & 1;
    int oh = (2 * wh + i + 1) & 7, ow = (2 * ww + j + 1) & 7, od = (2 * wd + k + 1) & 7;
    ntok[lane] = oh * 64 + ow * 8 + od;
  }
  __syncthreads();
  #pragma unroll
  for (int t = 0; t < 8; t++) {
    long base = ((long)b * 512 + ntok[t]) * 1152 + h * 64 + lane;
    qs[t][lane] = bf2f(qkv[base]);
    ks[t][lane] = bf2f(qkv[base + 384]);
    vs[t][lane] = bf2f(qkv[base + 768]);
  }
  __syncthreads();
  const int tq = lane >> 3, tm = lane & 7;
  float sc = 0.f;
  #pragma unroll 16
  for (int d = 0; d < 64; d++) sc += qs[tq][d] * ks[tm][d];
  sc *= 0.125f;
  float mx = sc;
  mx = fmaxf(mx, __shfl_xor(mx, 4));
  mx = fmaxf(mx, __shfl_xor(mx, 2));
  mx = fmaxf(mx, __shfl_xor(mx, 1));
  float e = __expf(sc - mx);
  float sm = e;
  sm += __shfl_xor(sm, 4); sm += __shfl_xor(sm, 2); sm += __shfl_xor(sm, 1);
  attw[tq][tm] = e / sm;
  __syncthreads();
  #pragma unroll
  for (int t = 0; t < 8; t++) {
    float o = 0.f;
    #pragma unroll
    for (int m = 0; m < 8; m++) o += attw[t][m] * vs[m][lane];
    attno[((long)b * 512 + ntok[t]) * 384 + h * 64 + lane] = f2bf(o);
  }
}

__global__ __launch_bounds__(256) void im2col_k(const float* __restrict__ x, u16* __restrict__ xp) {
  const int i = blockIdx.x * 256 + threadIdx.x;
  const int l = i & 511; const int m = i >> 9;
  const int b = m >> 9, n = m & 511;
  const int h = n >> 6, w = (n >> 3) & 7, d = n & 7;
  const int pi = l >> 6, pj = (l >> 3) & 7, pk = l & 7;
  xp[i] = f2bf(x[(long)b * 262144 + (long)(h * 8 + pi) * 4096 + (w * 8 + pj) * 64 + (d * 8 + pk)]);
}

__global__ __launch_bounds__(256) void castw_k(const float* __restrict__ in, u16* __restrict__ out, int n) {
  for (int i = blockIdx.x * 256 + threadIdx.x; i < n; i += gridDim.x * 256)
    out[i] = f2bf(in[i]);
}

// out_w [15][384] fp32 -> owT [16][384] bf16 (row 15 zero)
__global__ __launch_bounds__(256) void owrep_k(const float* __restrict__ ow, u16* __restrict__ owT) {
  const int i = blockIdx.x * 256 + threadIdx.x;
  if (i < 6144) owT[i] = (i < 5760) ? f2bf(ow[i]) : (u16)0;
}

// LDS-tiled transpose+cast for the 7 [z=4][K][N] weights -> [z][N][K] bf16.
struct TJ { const float* s[7]; u16* d[7]; };
__global__ __launch_bounds__(256) void transpose_tiled_k(TJ tj) {
  __shared__ u16 tile[64][65];
  const int cumt[8] = {0, 432, 576, 720, 1296, 1872, 2448, 3024};
  const int bi = blockIdx.x;
  int j = 0;
  #pragma unroll
  for (int t = 1; t < 7; t++) if (bi >= cumt[t]) j = t;
  const int li = bi - cumt[j];
  const int Kj = (j >= 5) ? 1536 : 384;
  const int Nj = (j == 0) ? 1152 : ((j == 3 || j == 4) ? 1536 : 384);
  const int tn_cnt = Nj >> 6;
  const int per_z = (Kj >> 6) * tn_cnt;
  const int z = li / per_z;
  int rem = li - z * per_z;
  const int tk = rem / tn_cnt, tn = rem - tk * tn_cnt;
  const float* src = tj.s[j] + (long)z * Kj * Nj;
  u16* dst = tj.d[j] + (long)z * Kj * Nj;
  const int k0 = tk << 6, n0 = tn << 6;
  const int rl = threadIdx.x >> 6, c = threadIdx.x & 63;
  #pragma unroll
  for (int i = 0; i < 16; i++) {
    int r = i * 4 + rl;
    tile[r][c] = f2bf(src[(long)(k0 + r) * Nj + n0 + c]);
  }
  __syncthreads();
  #pragma unroll
  for (int i = 0; i < 16; i++) {
    int n = i * 4 + rl;
    dst[(long)(n0 + n) * Kj + k0 + c] = tile[c][n];
  }
}

// dense per-head qkv weights -> [4][1152][384] bf16, LDS-tiled. 432 blocks.
__global__ __launch_bounds__(256) void repack_mqkv_k2(const float* __restrict__ qw, const float* __restrict__ kw,
                                                      const float* __restrict__ vw, u16* __restrict__ out) {
  __shared__ u16 tile[64][65];
  const int bi = blockIdx.x;
  const int j = bi / 108;
  int rem = bi - j * 108;
  const int s = rem / 36; rem -= s * 36;
  const int h = rem / 6, tk = rem - h * 6;
  const float* src = (s == 0 ? qw : s == 1 ? kw : vw) + (long)j * 147456;
  const int rl = threadIdx.x >> 6, cc = threadIdx.x & 63;
  #pragma unroll
  for (int i = 0; i < 16; i++) {
    int cl = tk * 64 + i * 4 + rl;
    tile[i * 4 + rl][cc] = f2bf(src[(long)(h * 384 + cl) * 64 + cc]);
  }
  __syncthreads();
  u16* ob = out + (long)j * 442368 + (long)(s * 384 + h * 64) * 384 + tk * 64;
  #pragma unroll
  for (int i = 0; i < 16; i++) {
    int d = i * 4 + rl;
    ob[(long)d * 384 + cc] = tile[cc][d];
  }
}

// both deconv weights [C][O][2][2][2] -> [8][O][C] bf16, one launch (144 blocks).
__global__ __launch_bounds__(256) void repack_dw2_k(const float* __restrict__ in1, u16* __restrict__ out1,
                                                    const float* __restrict__ in2, u16* __restrict__ out2) {
  __shared__ u16 ds[32][514];
  const int sel = blockIdx.x >= 72;
  const float* in = sel ? in2 : in1;
  u16* out = sel ? out2 : out1;
  const int bx = sel ? blockIdx.x - 72 : blockIdx.x;
  const int bo = bx % 6, bc = bx / 6;
  const int c0 = bc * 32, o0 = bo * 64;
  #pragma unroll 4
  for (int it = 0; it < 64; it++) {
    int fl = it * 256 + threadIdx.x;
    int cr = fl >> 9, mm = fl & 511;
    ds[cr][mm] = f2bf(in[(long)(c0 + cr) * 3072 + o0 * 8 + mm]);
  }
  __syncthreads();
  #pragma unroll 4
  for (int it = 0; it < 64; it++) {
    int fl = it * 256 + threadIdx.x;
    int ijk = fl >> 11, rem = fl & 2047;
    int oo = rem >> 5, cr = rem & 31;
    out[(long)ijk * 147456 + (long)(o0 + oo) * 384 + c0 + cr] = ds[cr][oo * 8 + ijk];
  }
}

// ---------------------------------------------------------------------------

static MmP mk(const u16* A, const u16* Bt, const float* bias, void* C,
              int K, int lda, int ldb, int ldc) {
  MmP p{};
  p.A = A; p.Bt = Bt; p.bias = bias; p.C = C; p.aux = nullptr;
  p.e1 = p.e2 = p.e3 = p.e4 = nullptr;
  p.K = K; p.ZH = 1; p.lda = lda; p.ldb = ldb; p.ldc = ldc;
  p.aSb = p.aSh = p.bSb = p.bSh = p.cSb = p.cSh = 0;
  return p;
}

extern "C" void kernel_launch(void* const* d_in, const int* in_sizes, int n_in,
                              void* d_out, int out_size, void* d_ws, size_t ws_size,
                              hipStream_t stream) {
  (void)in_sizes; (void)n_in; (void)out_size; (void)ws_size;
  const float* x        = (const float*)d_in[0];
  const float* patch_w  = (const float*)d_in[1];
  const float* patch_b  = (const float*)d_in[2];
  const float* pos_emb  = (const float*)d_in[3];
  const float* m_ln1_g  = (const float*)d_in[4];
  const float* m_ln1_b  = (const float*)d_in[5];
  const float* m_qw     = (const float*)d_in[6];
  const float* m_kw     = (const float*)d_in[7];
  const float* m_vw     = (const float*)d_in[8];
  const float* m_proj_w = (const float*)d_in[9];
  const float* m_proj_b = (const float*)d_in[10];
  const float* m_ln2_g  = (const float*)d_in[11];
  const float* m_ln2_b  = (const float*)d_in[12];
  const float* m_w1     = (const float*)d_in[13];
  const float* m_b1     = (const float*)d_in[14];
  const float* m_w2     = (const float*)d_in[15];
  const float* m_b2     = (const float*)d_in[16];
  const float* s_ln1_g  = (const float*)d_in[17];
  const float* s_ln1_b  = (const float*)d_in[18];
  const float* s_qkv_w  = (const float*)d_in[19];
  const float* s_qkv_b  = (const float*)d_in[20];
  const float* s_proj_w = (const float*)d_in[21];
  const float* s_proj_b = (const float*)d_in[22];
  const float* s_ln2_g  = (const float*)d_in[23];
  const float* s_ln2_b  = (const float*)d_in[24];
  const float* s_w1     = (const float*)d_in[25];
  const float* s_b1     = (const float*)d_in[26];
  const float* s_w2     = (const float*)d_in[27];
  const float* s_b2     = (const float*)d_in[28];
  const float* d1_w     = (const float*)d_in[29];
  const float* d1_b     = (const float*)d_in[30];
  const float* bn1_g    = (const float*)d_in[31];
  const float* bn1_b    = (const float*)d_in[32];
  const float* bn1_m    = (const float*)d_in[33];
  const float* bn1_v    = (const float*)d_in[34];
  const float* d2_w     = (const float*)d_in[35];
  const float* d2_b     = (const float*)d_in[36];
  const float* bn2_g    = (const float*)d_in[37];
  const float* bn2_b    = (const float*)d_in[38];
  const float* bn2_m    = (const float*)d_in[39];
  const float* bn2_v    = (const float*)d_in[40];
  const float* out_w    = (const float*)d_in[41];
  const float* out_b    = (const float*)d_in[42];
  float* out = (float*)d_out;

  // ---- workspace arena ----
  char* wsp = (char*)d_ws;
  auto alloc = [&](size_t bytes) { void* p = wsp; wsp += (bytes + 255) & ~(size_t)255; return p; };
  float* tok    = (float*)alloc(786432 * 4);
  u16* wqkv_m   = (u16*)alloc(1769472 * 2);
  u16* wqkv_s   = (u16*)alloc(1769472 * 2);
  u16* wproj_m  = (u16*)alloc(589824 * 2);
  u16* wproj_s  = (u16*)alloc(589824 * 2);
  u16* w1m      = (u16*)alloc(2359296 * 2);
  u16* w1s      = (u16*)alloc(2359296 * 2);
  u16* w2m      = (u16*)alloc(2359296 * 2);
  u16* w2s      = (u16*)alloc(2359296 * 2);
  u16* wpatch   = (u16*)alloc(196608 * 2);
  u16* wd1      = (u16*)alloc(1179648 * 2);
  u16* wd2      = (u16*)alloc(1179648 * 2);
  u16* owT      = (u16*)alloc(6144 * 2);
  u16* lnb      = (u16*)alloc(786432 * 2);
  u16* qkvb     = (u16*)alloc(2359296 * 2);
  u16* attnob   = (u16*)alloc(786432 * 2);
  u16* ffnhb    = (u16*)alloc(3145728 * 2);
  u16* scoresb  = (u16*)alloc(6291456 * 2);   // 24x512x512; aliased by xp / y1b
  u16* vTb      = (u16*)alloc(786432 * 2);    // aliased by tokb (late)
  u16* xpb   = scoresb;
  u16* y1b   = scoresb;
  u16* tokb  = vTb;

  // ---- weight repack (all LDS-tiled, coalesced) ----
  castw_k<<<256, 256, 0, stream>>>(patch_w, wpatch, 196608);
  repack_mqkv_k2<<<432, 256, 0, stream>>>(m_qw, m_kw, m_vw, wqkv_m);
  {
    TJ tj;
    tj.s[0] = s_qkv_w;  tj.d[0] = wqkv_s;
    tj.s[1] = m_proj_w; tj.d[1] = wproj_m;
    tj.s[2] = s_proj_w; tj.d[2] = wproj_s;
    tj.s[3] = m_w1;     tj.d[3] = w1m;
    tj.s[4] = s_w1;     tj.d[4] = w1s;
    tj.s[5] = m_w2;     tj.d[5] = w2m;
    tj.s[6] = s_w2;     tj.d[6] = w2s;
    transpose_tiled_k<<<3024, 256, 0, stream>>>(tj);
  }
  repack_dw2_k<<<144, 256, 0, stream>>>(d1_w, wd1, d2_w, wd2);
  owrep_k<<<24, 256, 0, stream>>>(out_w, owT);

  // ---- patch embedding + pos_emb -> tok (fp32) ----
  im2col_k<<<4096, 256, 0, stream>>>(x, xpb);
  {
    MmP p = mk(xpb, wpatch, patch_b, tok, 512, 512, 512, 384);
    p.e1 = pos_emb;
    mfma_gemm<1, 64><<<dim3(6, 32, 1), 256, 0, stream>>>(p);
  }

  for (int j = 0; j < 4; j++) {
    // ======== dense block ========
    ln_k<<<512, 256, 0, stream>>>(tok, m_ln1_g + j * 384, m_ln1_b + j * 384, lnb);
    {  // QKV (no bias) + fused vT scatter
      MmP p = mk(lnb, wqkv_m + (long)j * 442368, nullptr, qkvb, 384, 384, 384, 1152);
      p.aux = vTb;
      mfma_gemm<7, 128><<<dim3(18, 16, 1), 256, 0, stream>>>(p);
    }
    attnsm_k<<<dim3(8, 24, 1), 256, 0, stream>>>(qkvb, scoresb);
    {  // attno = P V per (b,h): M=512 N=64 K=512
      MmP p = mk(scoresb, vTb, nullptr, attnob, 512, 512, 512, 384);
      p.ZH = 6; p.aSb = 1572864; p.aSh = 262144; p.bSb = 196608; p.bSh = 32768;
      p.cSb = 196608; p.cSh = 64;
      mfma_gemm<0, 64><<<dim3(1, 8, 24), 256, 0, stream>>>(p);
    }
    {  // proj + residual -> tok fp32
      MmP p = mk(attnob, wproj_m + (long)j * 147456, m_proj_b + j * 384, tok, 384, 384, 384, 384);
      mfma_gemm<2, 64><<<dim3(6, 32, 1), 256, 0, stream>>>(p);
    }
    ln_k<<<512, 256, 0, stream>>>(tok, m_ln2_g + j * 384, m_ln2_b + j * 384, lnb);
    {  // FFN1 relu
      MmP p = mk(lnb, w1m + (long)j * 589824, m_b1 + j * 1536, ffnhb, 384, 384, 384, 1536);
      mfma_gemm<3, 128><<<dim3(24, 16, 1), 256, 0, stream>>>(p);
    }
    {  // FFN2 + residual
      MmP p = mk(ffnhb, w2m + (long)j * 589824, m_b2 + j * 384, tok, 1536, 1536, 1536, 384);
      mfma_gemm<2, 64><<<dim3(6, 32, 1), 256, 0, stream>>>(p);
    }

    // ======== shifted-window block ========
    ln_k<<<512, 256, 0, stream>>>(tok, s_ln1_g + j * 384, s_ln1_b + j * 384, lnb);
    {
      MmP p = mk(lnb, wqkv_s + (long)j * 442368, s_qkv_b + j * 1152, qkvb, 384, 384, 384, 1152);
      mfma_gemm<0, 128><<<dim3(18, 16, 1), 256, 0, stream>>>(p);
    }
    swin_k<<<1536, 64, 0, stream>>>(qkvb, attnob);
    {
      MmP p = mk(attnob, wproj_s + (long)j * 147456, s_proj_b + j * 384, tok, 384, 384, 384, 384);
      mfma_gemm<2, 64><<<dim3(6, 32, 1), 256, 0, stream>>>(p);
    }
    ln_k<<<512, 256, 0, stream>>>(tok, s_ln2_g + j * 384, s_ln2_b + j * 384, lnb);
    {
      MmP p = mk(lnb, w1s + (long)j * 589824, s_b1 + j * 1536, ffnhb, 384, 384, 384, 1536);
      mfma_gemm<3, 128><<<dim3(24, 16, 1), 256, 0, stream>>>(p);
    }
    {
      MmP p = mk(ffnhb, w2s + (long)j * 589824, s_b2 + j * 384, tok, 1536, 1536, 1536, 384);
      mfma_gemm<2, 64><<<dim3(6, 32, 1), 256, 0, stream>>>(p);
    }
  }

  // ---- decoder ----
  castw_k<<<768, 256, 0, stream>>>(tok, tokb, 786432);
  {  // deconv1 all 8 positions + bn1-relu -> y1b token-major
    MmP p = mk(tokb, wd1, d1_b, y1b, 384, 384, 384, 384);
    p.ZH = 8; p.bSh = 147456;
    p.e1 = bn1_g; p.e2 = bn1_b; p.e3 = bn1_m; p.e4 = bn1_v;
    mfma_gemm<5, 128><<<dim3(6, 16, 8), 256, 0, stream>>>(p);
  }
  // fused deconv2 + bn2 + relu + MFMA contraction
  dc2_k<<<dim3(256, 8, 1), 512, 0, stream>>>(y1b, wd2, d2_b, bn2_g, bn2_b, bn2_m, bn2_v,
                                             owT, out_b, out);
}